// Round 1
// baseline (212.184 us; speedup 1.0000x reference)
//
#include <hip/hip_runtime.h>
#include <hip/hip_bf16.h>
#include <math.h>

// Problem constants
#define Q_N 100
#define G_N 50
#define P_N 24
#define RS_N 96
#define GH 72
#define GW 128
#define GRID_N (GH*GW)   // 9216
#define THICK 0.03f
#define SHARP 80.0f
#define PTS_W 5.0f
#define TAN_W 1.0f
#define CURV_W 0.5f
#define OVL_W 2.0f

// Workspace layout (in floats)
#define PRS_OFF 0                       // pred_rs: 100*96*2 = 19200
#define GRS_OFF 19200                   // gt_rs:   50*96*2  = 9600
#define PM_OFF  28800                   // pm: 100*9216 = 921600
#define GM_OFF  950400                  // gm:  50*9216 = 460800
#define PMS_OFF 1411200                 // pm row sums: 100
#define GMS_OFF 1411300                 // gm row sums: 50
#define MGT_OFF 1411350                 // m_gt: 50*24 = 1200
// total: 1412550 floats = 5.65 MB

__device__ __forceinline__ float smooth_l1(float x) {
    float a = fabsf(x);
    return (a < 1.0f) ? 0.5f * a * a : a - 0.5f;
}

// ---------------- Kernel 1: mask + resample (one block per lane) ----------------
__global__ void prep_kernel(const float* __restrict__ pred,
                            const float* __restrict__ gt,
                            const float* __restrict__ vis,
                            float* __restrict__ ws) {
    int lane = blockIdx.x;              // 0..149
    int tid = threadIdx.x;
    bool isPred = lane < Q_N;
    __shared__ float px[P_N], py[P_N], pmask[P_N];
    __shared__ float cum[P_N];
    __shared__ float s_total;

    const float* src = isPred ? pred + lane * (P_N*2) : gt + (lane - Q_N) * (P_N*2);
    if (tid < P_N) {
        px[tid] = src[2*tid];
        py[tid] = src[2*tid+1];
        pmask[tid] = 1.0f;
    }
    __syncthreads();
    if (!isPred && tid == 0) {
        const float* v = vis + (lane - Q_N) * P_N;
        int cnt = 0;
        for (int k = 0; k < P_N; k++) {
            int r = (v[k] > 0.5f) ? 1 : 0;
            cnt += r;
            pmask[k] = (float)r;
        }
        if (cnt < 2) {
            for (int k = 0; k < P_N; k++) pmask[k] = 1.0f;
        }
        float* mg = ws + MGT_OFF + (lane - Q_N) * P_N;
        for (int k = 0; k < P_N; k++) mg[k] = pmask[k];
    }
    __syncthreads();
    if (tid == 0) {
        float c = 0.0f;
        cum[0] = 0.0f;
        for (int k = 0; k < P_N-1; k++) {
            float dx = px[k+1]-px[k], dy = py[k+1]-py[k];
            float dd = dx*dx + dy*dy;
            float len = sqrtf(fmaxf(dd, 1e-12f));        // _safe_norm
            float valid = pmask[k]*pmask[k+1];           // 0 or 1
            c += len * valid;
            cum[k+1] = c;
        }
        s_total = c;
    }
    __syncthreads();
    float total = s_total;
    if (tid < RS_N) {
        float ox, oy;
        if (total < 1e-8f) {
            ox = px[0]; oy = py[0];
        } else {
            float t = ((float)tid / 95.0f) * total;
            // searchsorted(cum, t, side='right') - 1 == count(cum <= t) - 1
            int idx = -1;
            for (int k = 0; k < P_N; k++) idx += (cum[k] <= t) ? 1 : 0;
            idx = min(max(idx, 0), P_N-2);
            float lt = cum[idx], rt = cum[idx+1];
            float alpha = (t - lt) / fmaxf(rt - lt, 1e-8f);
            ox = px[idx] + alpha * (px[idx+1]-px[idx]);
            oy = py[idx] + alpha * (py[idx+1]-py[idx]);
        }
        float* dst = isPred ? ws + PRS_OFF + lane * (RS_N*2)
                            : ws + GRS_OFF + (lane - Q_N) * (RS_N*2);
        dst[2*tid]   = ox;
        dst[2*tid+1] = oy;
    }
}

// ---------------- Kernel 2: soft masks (36 blocks of 256 per lane) ----------------
__global__ void softmask_kernel(const float* __restrict__ pred,
                                const float* __restrict__ gt,
                                float* __restrict__ ws) {
    int lane  = blockIdx.x / 36;        // 0..149
    int chunk = blockIdx.x % 36;
    int tid = threadIdx.x;
    bool isPred = lane < Q_N;
    __shared__ float px[P_N], py[P_N], pv[P_N], segv[P_N-1];
    __shared__ int s_noseg;

    if (tid == 0) {
        const float* src = isPred ? pred + lane * (P_N*2) : gt + (lane - Q_N) * (P_N*2);
        for (int k = 0; k < P_N; k++) { px[k] = src[2*k]; py[k] = src[2*k+1]; }
        const float* mg = ws + MGT_OFF + (lane - Q_N) * P_N;
        for (int k = 0; k < P_N; k++) pv[k] = isPred ? 1.0f : mg[k];
        int noseg = 1;
        for (int k = 0; k < P_N-1; k++) {
            float v = (pv[k]*pv[k+1] > 0.5f) ? 1.0f : 0.0f;
            segv[k] = v;
            if (v > 0.5f) noseg = 0;
        }
        s_noseg = noseg;
    }
    __syncthreads();

    int g  = chunk * 256 + tid;         // 0..9215
    int gi = g >> 7;                    // row (y)
    int gj = g & 127;                   // col (x)
    float x = (float)gj * (1.0f/127.0f);
    float y = (float)gi * (1.0f/71.0f);

    float mind = INFINITY;
    for (int k = 0; k < P_N-1; k++) {
        if (segv[k] > 0.5f) {
            float ax = px[k], ay = py[k];
            float abx = px[k+1]-ax, aby = py[k+1]-ay;
            float denom = fmaxf(abx*abx + aby*aby, 1e-8f);
            float apx = x-ax, apy = y-ay;
            float t = fminf(fmaxf((apx*abx + apy*aby)/denom, 0.0f), 1.0f);
            float dx = apx - t*abx, dy = apy - t*aby;
            float d = sqrtf(fmaxf(dx*dx + dy*dy, 1e-12f));
            mind = fminf(mind, d);
        }
    }
    if (s_noseg) {
        mind = INFINITY;
        for (int k = 0; k < P_N; k++) {
            if (pv[k] > 0.5f) {
                float dx = x-px[k], dy = y-py[k];
                float d = sqrtf(fmaxf(dx*dx + dy*dy, 1e-12f));
                mind = fminf(mind, d);
            }
        }
    }
    float z = (THICK - mind) * SHARP;
    float s = 1.0f / (1.0f + expf(-z));
    if (isPred) ws[PM_OFF + lane * GRID_N + g] = s;
    else        ws[GM_OFF + (lane - Q_N) * GRID_N + g] = s;
}

// ---------------- Kernel 3: deterministic row sums ----------------
__global__ void rowsum_kernel(float* __restrict__ ws) {
    int lane = blockIdx.x;              // 0..149
    int tid = threadIdx.x;
    const float* row = (lane < Q_N) ? ws + PM_OFF + lane * GRID_N
                                    : ws + GM_OFF + (lane - Q_N) * GRID_N;
    float acc = 0.0f;
    for (int g = tid; g < GRID_N; g += 256) acc += row[g];
    __shared__ float red[256];
    red[tid] = acc;
    __syncthreads();
    for (int s = 128; s > 0; s >>= 1) {
        if (tid < s) red[tid] += red[tid + s];
        __syncthreads();
    }
    if (tid == 0) {
        if (lane < Q_N) ws[PMS_OFF + lane] = red[0];
        else            ws[GMS_OFF + (lane - Q_N)] = red[0];
    }
}

// ---------------- Kernel 4: per-pair cost (one block per (i,j)) ----------------
__global__ void pair_kernel(const float* __restrict__ ws, float* __restrict__ out) {
    int i = blockIdx.x / G_N;
    int j = blockIdx.x % G_N;
    int tid = threadIdx.x;
    __shared__ float Ax[RS_N], Ay[RS_N], Bx[RS_N], By[RS_N];

    const float* A = ws + PRS_OFF + i * (RS_N*2);
    const float* B = ws + GRS_OFF + j * (RS_N*2);
    if (tid < RS_N)            { Ax[tid] = A[2*tid]; Ay[tid] = A[2*tid+1]; }
    else if (tid < 2*RS_N)     { int p = tid - RS_N; Bx[p] = B[2*p]; By[p] = B[2*p+1]; }
    __syncthreads();

    float acc_sym1 = 0.0f, acc_sym2 = 0.0f, acc_tan = 0.0f, acc_curv = 0.0f, acc_inter = 0.0f;

    // symmetric chamfer: point->polyline min distances
    if (tid < RS_N) {
        float x = Ax[tid], y = Ay[tid];
        float mind = INFINITY;
        for (int s = 0; s < RS_N-1; s++) {
            float ax = Bx[s], ay = By[s];
            float abx = Bx[s+1]-ax, aby = By[s+1]-ay;
            float denom = fmaxf(abx*abx + aby*aby, 1e-8f);
            float apx = x-ax, apy = y-ay;
            float t = fminf(fmaxf((apx*abx + apy*aby)/denom, 0.0f), 1.0f);
            float dx = apx - t*abx, dy = apy - t*aby;
            mind = fminf(mind, sqrtf(fmaxf(dx*dx + dy*dy, 1e-12f)));
        }
        acc_sym1 = mind;
    } else if (tid < 2*RS_N) {
        int p = tid - RS_N;
        float x = Bx[p], y = By[p];
        float mind = INFINITY;
        for (int s = 0; s < RS_N-1; s++) {
            float ax = Ax[s], ay = Ay[s];
            float abx = Ax[s+1]-ax, aby = Ay[s+1]-ay;
            float denom = fmaxf(abx*abx + aby*aby, 1e-8f);
            float apx = x-ax, apy = y-ay;
            float t = fminf(fmaxf((apx*abx + apy*aby)/denom, 0.0f), 1.0f);
            float dx = apx - t*abx, dy = apy - t*aby;
            mind = fminf(mind, sqrtf(fmaxf(dx*dx + dy*dy, 1e-12f)));
        }
        acc_sym2 = mind;
    }

    // tangent alignment
    if (tid < RS_N) {
        int p = tid;
        int l = (p == 0) ? 0 : p-1;
        int r = (p == RS_N-1) ? RS_N-1 : p+1;
        float tax = Ax[r]-Ax[l], tay = Ay[r]-Ay[l];
        float na = fmaxf(sqrtf(tax*tax + tay*tay), 1e-8f);
        tax /= na; tay /= na;
        float tbx = Bx[r]-Bx[l], tby = By[r]-By[l];
        float nb = fmaxf(sqrtf(tbx*tbx + tby*tby), 1e-8f);
        tbx /= nb; tby /= nb;
        acc_tan = fabsf(tax*tbx + tay*tby);
    }

    // curvature (second differences)
    if (tid < RS_N-2) {
        int p = tid;
        float psx = Ax[p+2] - 2.0f*Ax[p+1] + Ax[p];
        float psy = Ay[p+2] - 2.0f*Ay[p+1] + Ay[p];
        float gsx = Bx[p+2] - 2.0f*Bx[p+1] + Bx[p];
        float gsy = By[p+2] - 2.0f*By[p+1] + By[p];
        acc_curv = smooth_l1(psx - gsx) + smooth_l1(psy - gsy);
    }

    // mask intersection dot product
    {
        const float* pmr = ws + PM_OFF + i * GRID_N;
        const float* gmr = ws + GM_OFF + j * GRID_N;
        for (int g = tid; g < GRID_N; g += 256) acc_inter += pmr[g] * gmr[g];
    }

    // 5-channel block reduction
    __shared__ float red[5*256];
    red[0*256+tid] = acc_sym1;
    red[1*256+tid] = acc_sym2;
    red[2*256+tid] = acc_tan;
    red[3*256+tid] = acc_curv;
    red[4*256+tid] = acc_inter;
    __syncthreads();
    for (int s = 128; s > 0; s >>= 1) {
        if (tid < s) {
            red[0*256+tid] += red[0*256+tid+s];
            red[1*256+tid] += red[1*256+tid+s];
            red[2*256+tid] += red[2*256+tid+s];
            red[3*256+tid] += red[3*256+tid+s];
            red[4*256+tid] += red[4*256+tid+s];
        }
        __syncthreads();
    }
    if (tid == 0) {
        float sym  = 0.5f * (red[0*256] / (float)RS_N + red[1*256] / (float)RS_N);
        float tan  = 1.0f - red[2*256] / (float)RS_N;
        float curv = red[3*256] / (float)((RS_N-2)*2);
        float inter = red[4*256];
        float uni = ws[PMS_OFF + i] + ws[GMS_OFF + j] - inter;
        float overlap = 1.0f - inter / fmaxf(uni, 1e-8f);
        out[i * G_N + j] = PTS_W * sym + TAN_W * tan + CURV_W * curv + OVL_W * overlap;
    }
}

extern "C" void kernel_launch(void* const* d_in, const int* in_sizes, int n_in,
                              void* d_out, int out_size, void* d_ws, size_t ws_size,
                              hipStream_t stream) {
    (void)in_sizes; (void)n_in; (void)out_size; (void)ws_size;
    const float* pred = (const float*)d_in[0];
    const float* gt   = (const float*)d_in[1];
    const float* vis  = (const float*)d_in[2];
    float* out = (float*)d_out;
    float* ws  = (float*)d_ws;

    prep_kernel<<<Q_N + G_N, 128, 0, stream>>>(pred, gt, vis, ws);
    softmask_kernel<<<(Q_N + G_N) * 36, 256, 0, stream>>>(pred, gt, ws);
    rowsum_kernel<<<Q_N + G_N, 256, 0, stream>>>(ws);
    pair_kernel<<<Q_N * G_N, 256, 0, stream>>>(ws, out);
}

// Round 2
// 84.189 us; speedup vs baseline: 2.5203x; 2.5203x over previous
//
#include <hip/hip_runtime.h>
#include <hip/hip_bf16.h>
#include <math.h>

// Problem constants
#define Q_N 100
#define G_N 50
#define P_N 24
#define RS_N 96
#define GH 72
#define GW 128
#define GRID_N (GH*GW)   // 9216
#define THICK 0.03f
#define SHARP 80.0f
#define PTS_W 5.0f
#define TAN_W 1.0f
#define CURV_W 0.5f
#define OVL_W 2.0f

// Workspace layout (in floats)
#define PRS_OFF 0                       // pred_rs: 100*96*2 = 19200
#define GRS_OFF 19200                   // gt_rs:   50*96*2  = 9600
#define PM_OFF  28800                   // pm: 100*9216 = 921600
#define GM_OFF  950400                  // gm:  50*9216 = 460800
#define PMS_OFF 1411200                 // pm row sums: 100
#define GMS_OFF 1411300                 // gm row sums: 50
#define MGT_OFF 1411350                 // m_gt: 50*24 = 1200

__device__ __forceinline__ float smooth_l1(float x) {
    float a = fabsf(x);
    return (a < 1.0f) ? 0.5f * a * a : a - 0.5f;
}

// ---------------- Kernel 1: mask + resample (one block per lane) ----------------
__global__ void prep_kernel(const float* __restrict__ pred,
                            const float* __restrict__ gt,
                            const float* __restrict__ vis,
                            float* __restrict__ ws) {
    int lane = blockIdx.x;              // 0..149
    int tid = threadIdx.x;
    bool isPred = lane < Q_N;
    __shared__ float px[P_N], py[P_N], pmask[P_N];
    __shared__ float cum[P_N];
    __shared__ float s_total;

    const float* src = isPred ? pred + lane * (P_N*2) : gt + (lane - Q_N) * (P_N*2);
    if (tid < P_N) {
        float2 p = ((const float2*)src)[tid];
        px[tid] = p.x;
        py[tid] = p.y;
        pmask[tid] = 1.0f;
    }
    __syncthreads();
    if (!isPred && tid == 0) {
        const float* v = vis + (lane - Q_N) * P_N;
        int cnt = 0;
        for (int k = 0; k < P_N; k++) {
            int r = (v[k] > 0.5f) ? 1 : 0;
            cnt += r;
            pmask[k] = (float)r;
        }
        if (cnt < 2) {
            for (int k = 0; k < P_N; k++) pmask[k] = 1.0f;
        }
        float* mg = ws + MGT_OFF + (lane - Q_N) * P_N;
        for (int k = 0; k < P_N; k++) mg[k] = pmask[k];
    }
    __syncthreads();
    if (tid == 0) {
        float c = 0.0f;
        cum[0] = 0.0f;
        for (int k = 0; k < P_N-1; k++) {
            float dx = px[k+1]-px[k], dy = py[k+1]-py[k];
            float dd = dx*dx + dy*dy;
            float len = sqrtf(fmaxf(dd, 1e-12f));        // _safe_norm
            float valid = pmask[k]*pmask[k+1];           // 0 or 1
            c += len * valid;
            cum[k+1] = c;
        }
        s_total = c;
    }
    __syncthreads();
    float total = s_total;
    if (tid < RS_N) {
        float ox, oy;
        if (total < 1e-8f) {
            ox = px[0]; oy = py[0];
        } else {
            float t = ((float)tid / 95.0f) * total;
            // searchsorted(cum, t, side='right') - 1 == count(cum <= t) - 1
            int idx = -1;
            for (int k = 0; k < P_N; k++) idx += (cum[k] <= t) ? 1 : 0;
            idx = min(max(idx, 0), P_N-2);
            float lt = cum[idx], rt = cum[idx+1];
            float alpha = (t - lt) / fmaxf(rt - lt, 1e-8f);
            ox = px[idx] + alpha * (px[idx+1]-px[idx]);
            oy = py[idx] + alpha * (py[idx+1]-py[idx]);
        }
        float* dst = isPred ? ws + PRS_OFF + lane * (RS_N*2)
                            : ws + GRS_OFF + (lane - Q_N) * (RS_N*2);
        dst[2*tid]   = ox;
        dst[2*tid+1] = oy;
    }
}

// ---------------- Kernel 2: soft masks (36 blocks of 256 per lane) ----------------
__global__ void softmask_kernel(const float* __restrict__ pred,
                                const float* __restrict__ gt,
                                float* __restrict__ ws) {
    int lane  = blockIdx.x / 36;        // 0..149
    int chunk = blockIdx.x % 36;
    int tid = threadIdx.x;
    bool isPred = lane < Q_N;
    __shared__ float ptx[P_N], pty[P_N], pvv[P_N];
    __shared__ float4 seg[P_N-1];       // ax, ay, abx, aby (sentinel if invalid)
    __shared__ float  sinv[P_N-1];
    __shared__ int s_noseg;

    if (tid == 0) s_noseg = 1;
    if (tid < P_N) {
        const float* src = isPred ? pred + lane * (P_N*2) : gt + (lane - Q_N) * (P_N*2);
        float2 p = ((const float2*)src)[tid];
        ptx[tid] = p.x; pty[tid] = p.y;
        pvv[tid] = isPred ? 1.0f : ws[MGT_OFF + (lane - Q_N) * P_N + tid];
    }
    __syncthreads();
    if (tid < P_N-1) {
        bool v = pvv[tid] * pvv[tid+1] > 0.5f;
        if (v) {
            float ax = ptx[tid], ay = pty[tid];
            float abx = ptx[tid+1]-ax, aby = pty[tid+1]-ay;
            seg[tid] = make_float4(ax, ay, abx, aby);
            sinv[tid] = 1.0f / fmaxf(abx*abx + aby*aby, 1e-8f);
            s_noseg = 0;                 // benign race: all writers write 0
        } else {
            seg[tid] = make_float4(1e18f, 1e18f, 0.0f, 0.0f);  // far sentinel
            sinv[tid] = 0.0f;
        }
    }
    __syncthreads();

    int g  = chunk * 256 + tid;         // 0..9215
    int gi = g >> 7;                    // row (y)
    int gj = g & 127;                   // col (x)
    float x = (float)gj * (1.0f/127.0f);
    float y = (float)gi * (1.0f/71.0f);

    float mind2 = 3.0e38f;
    #pragma unroll
    for (int k = 0; k < P_N-1; k++) {
        float4 sg = seg[k];
        float inv = sinv[k];
        float apx = x - sg.x, apy = y - sg.y;
        float t = (apx*sg.z + apy*sg.w) * inv;
        t = fminf(fmaxf(t, 0.0f), 1.0f);
        float dx = apx - t*sg.z, dy = apy - t*sg.w;
        mind2 = fminf(mind2, dx*dx + dy*dy);
    }
    if (s_noseg) {
        mind2 = 3.0e38f;
        for (int k = 0; k < P_N; k++) {
            if (pvv[k] > 0.5f) {
                float dx = x - ptx[k], dy = y - pty[k];
                mind2 = fminf(mind2, dx*dx + dy*dy);
            }
        }
    }
    float mind = sqrtf(fmaxf(mind2, 1e-12f));
    float z = (THICK - mind) * SHARP;
    float s = 1.0f / (1.0f + expf(-z));
    if (isPred) ws[PM_OFF + lane * GRID_N + g] = s;
    else        ws[GM_OFF + (lane - Q_N) * GRID_N + g] = s;
}

// ---------------- Kernel 3: deterministic row sums (float4 loads) ----------------
__global__ void rowsum_kernel(float* __restrict__ ws) {
    int lane = blockIdx.x;              // 0..149
    int tid = threadIdx.x;
    const float4* row = (lane < Q_N) ? (const float4*)(ws + PM_OFF + lane * GRID_N)
                                     : (const float4*)(ws + GM_OFF + (lane - Q_N) * GRID_N);
    float acc = 0.0f;
    for (int g = tid; g < GRID_N/4; g += 256) {
        float4 v = row[g];
        acc += (v.x + v.y) + (v.z + v.w);
    }
    __shared__ float red[256];
    red[tid] = acc;
    __syncthreads();
    for (int s = 128; s > 0; s >>= 1) {
        if (tid < s) red[tid] += red[tid + s];
        __syncthreads();
    }
    if (tid == 0) {
        if (lane < Q_N) ws[PMS_OFF + lane] = red[0];
        else            ws[GMS_OFF + (lane - Q_N)] = red[0];
    }
}

// ---------------- Kernel 4: per-pair cost (one 192-thread block per (i,j)) ----------------
__global__ __launch_bounds__(192)
void pair_kernel(const float* __restrict__ ws, float* __restrict__ out) {
    int i = blockIdx.x / G_N;
    int j = blockIdx.x % G_N;
    int tid = threadIdx.x;              // 0..191
    __shared__ float Ax[RS_N], Ay[RS_N], Bx[RS_N], By[RS_N];
    __shared__ float4 Aseg[RS_N-1], Bseg[RS_N-1];
    __shared__ float  AInv[RS_N-1], BInv[RS_N-1];
    __shared__ float wred[3][4];

    const float* Abase = ws + PRS_OFF + i * (RS_N*2);
    const float* Bbase = ws + GRS_OFF + j * (RS_N*2);
    if (tid < RS_N) {
        float2 p = ((const float2*)Abase)[tid];
        Ax[tid] = p.x; Ay[tid] = p.y;
    } else {
        int p2 = tid - RS_N;
        float2 p = ((const float2*)Bbase)[p2];
        Bx[p2] = p.x; By[p2] = p.y;
    }
    __syncthreads();
    if (tid < RS_N-1) {
        float ax = Bx[tid], ay = By[tid];
        float abx = Bx[tid+1]-ax, aby = By[tid+1]-ay;
        Bseg[tid] = make_float4(ax, ay, abx, aby);
        BInv[tid] = 1.0f / fmaxf(abx*abx + aby*aby, 1e-8f);
    } else if (tid >= RS_N && tid < 2*RS_N-1) {
        int s = tid - RS_N;
        float ax = Ax[s], ay = Ay[s];
        float abx = Ax[s+1]-ax, aby = Ay[s+1]-ay;
        Aseg[s] = make_float4(ax, ay, abx, aby);
        AInv[s] = 1.0f / fmaxf(abx*abx + aby*aby, 1e-8f);
    }
    __syncthreads();

    // chamfer — identical instruction stream for both directions (no divergence)
    bool first = tid < RS_N;
    int p = first ? tid : tid - RS_N;
    const float*  PX = first ? Ax : Bx;
    const float*  PY = first ? Ay : By;
    const float4* SG = first ? Bseg : Aseg;
    const float*  SI = first ? BInv : AInv;
    float x = PX[p], y = PY[p];
    float mind2 = 3.0e38f;
    #pragma unroll 5
    for (int s = 0; s < RS_N-1; s++) {
        float4 sg = SG[s];
        float inv = SI[s];
        float apx = x - sg.x, apy = y - sg.y;
        float t = (apx*sg.z + apy*sg.w) * inv;
        t = fminf(fmaxf(t, 0.0f), 1.0f);
        float dx = apx - t*sg.z, dy = apy - t*sg.w;
        mind2 = fminf(mind2, dx*dx + dy*dy);
    }
    float cham = sqrtf(fmaxf(mind2, 1e-12f));

    // tangent alignment (tid < 96)
    float tanv = 0.0f;
    if (tid < RS_N) {
        int l = (tid == 0) ? 0 : tid-1;
        int r = (tid == RS_N-1) ? RS_N-1 : tid+1;
        float tax = Ax[r]-Ax[l], tay = Ay[r]-Ay[l];
        float na = fmaxf(sqrtf(tax*tax + tay*tay), 1e-8f);
        float tbx = Bx[r]-Bx[l], tby = By[r]-By[l];
        float nb = fmaxf(sqrtf(tbx*tbx + tby*tby), 1e-8f);
        tanv = fabsf((tax*tbx + tay*tby) / (na*nb));
    }

    // curvature (tid < 94)
    float curv = 0.0f;
    if (tid < RS_N-2) {
        float psx = Ax[tid+2] - 2.0f*Ax[tid+1] + Ax[tid];
        float psy = Ay[tid+2] - 2.0f*Ay[tid+1] + Ay[tid];
        float gsx = Bx[tid+2] - 2.0f*Bx[tid+1] + Bx[tid];
        float gsy = By[tid+2] - 2.0f*By[tid+1] + By[tid];
        curv = smooth_l1(psx - gsx) + smooth_l1(psy - gsy);
    }

    // mask intersection dot product (float4, all 192 threads, 12 iters)
    float inter = 0.0f;
    {
        const float4* pmr = (const float4*)(ws + PM_OFF + i * GRID_N);
        const float4* gmr = (const float4*)(ws + GM_OFF + j * GRID_N);
        for (int g = tid; g < GRID_N/4; g += 192) {
            float4 a = pmr[g], b = gmr[g];
            inter += a.x*b.x + a.y*b.y + a.z*b.z + a.w*b.w;
        }
    }

    // 4-channel reduction: wave shuffle then cross-wave via LDS
    #pragma unroll
    for (int off = 32; off > 0; off >>= 1) {
        cham  += __shfl_down(cham,  off);
        tanv  += __shfl_down(tanv,  off);
        curv  += __shfl_down(curv,  off);
        inter += __shfl_down(inter, off);
    }
    int w = tid >> 6;
    if ((tid & 63) == 0) {
        wred[w][0] = cham; wred[w][1] = tanv; wred[w][2] = curv; wred[w][3] = inter;
    }
    __syncthreads();
    if (tid == 0) {
        float c  = wred[0][0] + wred[1][0] + wred[2][0];
        float tt = wred[0][1] + wred[1][1] + wred[2][1];
        float cv = wred[0][2] + wred[1][2] + wred[2][2];
        float it = wred[0][3] + wred[1][3] + wred[2][3];
        float sym  = c / (float)(2*RS_N);          // == 0.5*(s1/96 + s2/96)
        float tan  = 1.0f - tt / (float)RS_N;
        float cu   = cv / (float)((RS_N-2)*2);
        float uni  = ws[PMS_OFF + i] + ws[GMS_OFF + j] - it;
        float overlap = 1.0f - it / fmaxf(uni, 1e-8f);
        out[i * G_N + j] = PTS_W * sym + TAN_W * tan + CURV_W * cu + OVL_W * overlap;
    }
}

extern "C" void kernel_launch(void* const* d_in, const int* in_sizes, int n_in,
                              void* d_out, int out_size, void* d_ws, size_t ws_size,
                              hipStream_t stream) {
    (void)in_sizes; (void)n_in; (void)out_size; (void)ws_size;
    const float* pred = (const float*)d_in[0];
    const float* gt   = (const float*)d_in[1];
    const float* vis  = (const float*)d_in[2];
    float* out = (float*)d_out;
    float* ws  = (float*)d_ws;

    prep_kernel<<<Q_N + G_N, 128, 0, stream>>>(pred, gt, vis, ws);
    softmask_kernel<<<(Q_N + G_N) * 36, 256, 0, stream>>>(pred, gt, ws);
    rowsum_kernel<<<Q_N + G_N, 256, 0, stream>>>(ws);
    pair_kernel<<<Q_N * G_N, 192, 0, stream>>>(ws, out);
}

// Round 4
// 82.682 us; speedup vs baseline: 2.5663x; 1.0182x over previous
//
#include <hip/hip_runtime.h>
#include <hip/hip_bf16.h>
#include <math.h>

// Problem constants
#define Q_N 100
#define G_N 50
#define P_N 24
#define RS_N 96
#define GH 72
#define GW 128
#define GRID_N (GH*GW)   // 9216
#define THICK 0.03f
#define SHARP 80.0f
#define PTS_W 5.0f
#define TAN_W 1.0f
#define CURV_W 0.5f
#define OVL_W 2.0f

// Workspace layout (in floats)
#define PRS_OFF 0                       // pred_rs: 100*96*2 = 19200
#define GRS_OFF 19200                   // gt_rs:   50*96*2  = 9600
#define PM_OFF  28800                   // pm: 100*9216 = 921600
#define GM_OFF  950400                  // gm:  50*9216 = 460800
#define PMS_OFF 1411200                 // pm row-sum partials: 100*4 = 400
#define GMS_OFF 1411600                 // gm row-sum partials: 50*4  = 200
#define MGT_OFF 1411800                 // m_gt: 50*24 = 1200  (ends 1413000)

__device__ __forceinline__ float smooth_l1(float x) {
    float a = fabsf(x);
    return (a < 1.0f) ? 0.5f * a * a : a - 0.5f;
}

// ---------------- Kernel 1: mask + resample (one block per lane) ----------------
__global__ void prep_kernel(const float* __restrict__ pred,
                            const float* __restrict__ gt,
                            const float* __restrict__ vis,
                            float* __restrict__ ws) {
    int lane = blockIdx.x;              // 0..149
    int tid = threadIdx.x;
    bool isPred = lane < Q_N;
    __shared__ float px[P_N], py[P_N], pmask[P_N];
    __shared__ float cum[P_N];
    __shared__ float s_total;

    const float* src = isPred ? pred + lane * (P_N*2) : gt + (lane - Q_N) * (P_N*2);
    if (tid < P_N) {
        float2 p = ((const float2*)src)[tid];
        px[tid] = p.x;
        py[tid] = p.y;
        pmask[tid] = 1.0f;
    }
    __syncthreads();
    if (!isPred && tid == 0) {
        const float* v = vis + (lane - Q_N) * P_N;
        int cnt = 0;
        for (int k = 0; k < P_N; k++) {
            int r = (v[k] > 0.5f) ? 1 : 0;
            cnt += r;
            pmask[k] = (float)r;
        }
        if (cnt < 2) {
            for (int k = 0; k < P_N; k++) pmask[k] = 1.0f;
        }
        float* mg = ws + MGT_OFF + (lane - Q_N) * P_N;
        for (int k = 0; k < P_N; k++) mg[k] = pmask[k];
    }
    __syncthreads();
    if (tid == 0) {
        float c = 0.0f;
        cum[0] = 0.0f;
        for (int k = 0; k < P_N-1; k++) {
            float dx = px[k+1]-px[k], dy = py[k+1]-py[k];
            float dd = dx*dx + dy*dy;
            float len = sqrtf(fmaxf(dd, 1e-12f));        // _safe_norm
            float valid = pmask[k]*pmask[k+1];           // 0 or 1
            c += len * valid;
            cum[k+1] = c;
        }
        s_total = c;
    }
    __syncthreads();
    float total = s_total;
    if (tid < RS_N) {
        float ox, oy;
        if (total < 1e-8f) {
            ox = px[0]; oy = py[0];
        } else {
            float t = ((float)tid / 95.0f) * total;
            // searchsorted(cum, t, side='right') - 1 == count(cum <= t) - 1
            int idx = -1;
            for (int k = 0; k < P_N; k++) idx += (cum[k] <= t) ? 1 : 0;
            idx = min(max(idx, 0), P_N-2);
            float lt = cum[idx], rt = cum[idx+1];
            float alpha = (t - lt) / fmaxf(rt - lt, 1e-8f);
            ox = px[idx] + alpha * (px[idx+1]-px[idx]);
            oy = py[idx] + alpha * (py[idx+1]-py[idx]);
        }
        float* dst = isPred ? ws + PRS_OFF + lane * (RS_N*2)
                            : ws + GRS_OFF + (lane - Q_N) * (RS_N*2);
        dst[2*tid]   = ox;
        dst[2*tid+1] = oy;
    }
}

// ---------------- Kernel 2: soft masks — 4 grid points per thread ----------------
__global__ void softmask_kernel(const float* __restrict__ pred,
                                const float* __restrict__ gt,
                                float* __restrict__ ws) {
    int lane  = blockIdx.x / 9;         // 0..149
    int chunk = blockIdx.x % 9;         // 0..8 (1024 grid pts each)
    int tid = threadIdx.x;              // 0..255
    bool isPred = lane < Q_N;
    __shared__ float ptx[P_N], pty[P_N], pvv[P_N];
    __shared__ float4 seg[P_N-1];
    __shared__ float  sinv[P_N-1];
    __shared__ int s_noseg;

    if (tid == 0) s_noseg = 1;
    if (tid < P_N) {
        const float* src = isPred ? pred + lane * (P_N*2) : gt + (lane - Q_N) * (P_N*2);
        float2 p = ((const float2*)src)[tid];
        ptx[tid] = p.x; pty[tid] = p.y;
        pvv[tid] = isPred ? 1.0f : ws[MGT_OFF + (lane - Q_N) * P_N + tid];
    }
    __syncthreads();
    if (tid < P_N-1) {
        bool v = pvv[tid] * pvv[tid+1] > 0.5f;
        if (v) {
            float ax = ptx[tid], ay = pty[tid];
            float abx = ptx[tid+1]-ax, aby = pty[tid+1]-ay;
            seg[tid] = make_float4(ax, ay, abx, aby);
            sinv[tid] = 1.0f / fmaxf(abx*abx + aby*aby, 1e-8f);
            s_noseg = 0;                 // benign race: all writers write 0
        } else {
            seg[tid] = make_float4(1e18f, 1e18f, 0.0f, 0.0f);  // far sentinel
            sinv[tid] = 0.0f;
        }
    }
    __syncthreads();

    int g0 = chunk * 1024 + tid * 4;    // 4 consecutive grid points
    float xs[4], ys[4], m2[4];
    #pragma unroll
    for (int u = 0; u < 4; u++) {
        int g = g0 + u;
        xs[u] = (float)(g & 127) * (1.0f/127.0f);
        ys[u] = (float)(g >> 7)  * (1.0f/71.0f);
        m2[u] = 3.0e38f;
    }
    for (int k = 0; k < P_N-1; k++) {
        float4 sg = seg[k];
        float inv = sinv[k];
        #pragma unroll
        for (int u = 0; u < 4; u++) {
            float apx = xs[u] - sg.x, apy = ys[u] - sg.y;
            float t = (apx*sg.z + apy*sg.w) * inv;
            t = fminf(fmaxf(t, 0.0f), 1.0f);
            float dx = apx - t*sg.z, dy = apy - t*sg.w;
            m2[u] = fminf(m2[u], dx*dx + dy*dy);
        }
    }
    if (s_noseg) {
        #pragma unroll
        for (int u = 0; u < 4; u++) m2[u] = 3.0e38f;
        for (int k = 0; k < P_N; k++) {
            if (pvv[k] > 0.5f) {
                #pragma unroll
                for (int u = 0; u < 4; u++) {
                    float dx = xs[u] - ptx[k], dy = ys[u] - pty[k];
                    m2[u] = fminf(m2[u], dx*dx + dy*dy);
                }
            }
        }
    }
    float4 o;
    float* ov = &o.x;
    #pragma unroll
    for (int u = 0; u < 4; u++) {
        float mind = sqrtf(fmaxf(m2[u], 1e-12f));
        float z = (THICK - mind) * SHARP;
        ov[u] = 1.0f / (1.0f + expf(-z));
    }
    float4* dst = (float4*)(ws + (isPred ? PM_OFF + lane * GRID_N
                                         : GM_OFF + (lane - Q_N) * GRID_N));
    dst[g0 >> 2] = o;
}

// ---------------- Kernel 3: row-sum partials (4 per row, deterministic) ----------------
__global__ void rowsum_kernel(float* __restrict__ ws) {
    int b = blockIdx.x;                 // 0..599
    int row = b >> 2, q = b & 3;
    int tid = threadIdx.x;              // 0..255
    const float4* base = (const float4*)(ws + ((row < Q_N) ? PM_OFF + row * GRID_N
                                                           : GM_OFF + (row - Q_N) * GRID_N));
    float acc = 0.0f;
    for (int t = tid; t < 576; t += 256) {
        float4 v = base[q*576 + t];
        acc += (v.x + v.y) + (v.z + v.w);
    }
    #pragma unroll
    for (int off = 32; off > 0; off >>= 1) acc += __shfl_down(acc, off);
    __shared__ float r4[4];
    if ((tid & 63) == 0) r4[tid >> 6] = acc;
    __syncthreads();
    if (tid == 0) {
        float s = (r4[0] + r4[1]) + (r4[2] + r4[3]);
        if (row < Q_N) ws[PMS_OFF + row*4 + q] = s;
        else           ws[GMS_OFF + (row - Q_N)*4 + q] = s;
    }
}

// ---------------- Kernel 4: 2x2 pair tile per 64-thread block ----------------
__global__ __launch_bounds__(64)
void pair_kernel(const float* __restrict__ ws, float* __restrict__ out) {
    int bi = blockIdx.x / 25;           // 0..49 -> i0 = 2*bi
    int bj = blockIdx.x % 25;           // 0..24 -> j0 = 2*bj
    int i0 = bi*2, j0 = bj*2;
    int l = threadIdx.x;                // 0..63 (one wave)

    __shared__ float Apts[2][RS_N*2];
    __shared__ float Bpts[2][RS_N*2];
    __shared__ float4 Aseg[2][RS_N-1];
    __shared__ float4 Bseg[2][RS_N-1];
    __shared__ float AInv[2][RS_N-1];
    __shared__ float BInv[2][RS_N-1];
    __shared__ float chamGrp[4][2];
    __shared__ float tanLds[4], curvLds[4], interLds[4];

    // stage 4 resampled polylines (192 float4 total)
    for (int q = l; q < 192; q += 64) {
        int side = q / 96;              // 0:A 1:B
        int r = (q / 48) & 1;           // row within tile
        int o = q % 48;                 // float4 within row
        const float4* src = (const float4*)(ws + (side ? (GRS_OFF + (j0+r)*(RS_N*2))
                                                       : (PRS_OFF + (i0+r)*(RS_N*2))));
        float4 v = src[o];
        float4* dst = (float4*)(side ? &Bpts[r][0] : &Apts[r][0]);
        dst[o] = v;
    }
    __syncthreads();
    // build 4 segment tables (380 entries)
    for (int q = l; q < 380; q += 64) {
        int side = q / 190;
        int rr = (q / 95) & 1;
        int s = q % 95;
        const float* P = side ? &Bpts[rr][0] : &Apts[rr][0];
        float ax = P[2*s], ay = P[2*s+1];
        float abx = P[2*s+2]-ax, aby = P[2*s+3]-ay;
        float inv = 1.0f / fmaxf(abx*abx + aby*aby, 1e-8f);
        if (side) { Bseg[rr][s] = make_float4(ax,ay,abx,aby); BInv[rr][s] = inv; }
        else      { Aseg[rr][s] = make_float4(ax,ay,abx,aby); AInv[rr][s] = inv; }
    }
    __syncthreads();

    // ---- chamfer: lane owns 6 points; 2 passes over opposing seg tables ----
    bool aSide = l < 32;
    int half = aSide ? l : l - 32;
    int own = half >> 4;                // which row of own tile
    int pb = (half & 15) * 6;           // first of 6 owned points
    const float* myP = aSide ? &Apts[own][0] : &Bpts[own][0];
    float PX[6], PY[6];
    #pragma unroll
    for (int q = 0; q < 6; q++) { PX[q] = myP[2*(pb+q)]; PY[q] = myP[2*(pb+q)+1]; }

    float chamPart0 = 0.0f, chamPart1 = 0.0f;
    #pragma unroll
    for (int pass = 0; pass < 2; pass++) {
        const float4* SG = aSide ? &Bseg[pass][0] : &Aseg[pass][0];
        const float*  SI = aSide ? &BInv[pass][0] : &AInv[pass][0];
        float m2[6];
        #pragma unroll
        for (int q = 0; q < 6; q++) m2[q] = 3.0e38f;
        for (int s = 0; s < 95; s++) {
            float4 sg = SG[s];
            float inv = SI[s];
            #pragma unroll
            for (int q = 0; q < 6; q++) {
                float apx = PX[q]-sg.x, apy = PY[q]-sg.y;
                float t = (apx*sg.z + apy*sg.w) * inv;
                t = fminf(fmaxf(t, 0.0f), 1.0f);
                float dx = apx - t*sg.z, dy = apy - t*sg.w;
                m2[q] = fminf(m2[q], dx*dx + dy*dy);
            }
        }
        float csum = 0.0f;
        #pragma unroll
        for (int q = 0; q < 6; q++) csum += sqrtf(fmaxf(m2[q], 1e-12f));
        if (pass == 0) chamPart0 = csum; else chamPart1 = csum;
    }
    // reduce within 16-lane groups (each group = one (side,row))
    #pragma unroll
    for (int off = 8; off > 0; off >>= 1) {
        chamPart0 += __shfl_down(chamPart0, off);
        chamPart1 += __shfl_down(chamPart1, off);
    }
    if ((l & 15) == 0) {
        int grp = l >> 4;               // 0,1 = A rows i0,i1 ; 2,3 = B rows j0,j1
        chamGrp[grp][0] = chamPart0;
        chamGrp[grp][1] = chamPart1;
    }

    // ---- tangent + curvature, one pass per pair ----
    for (int pp = 0; pp < 4; pp++) {
        const float* AX = &Apts[pp>>1][0];
        const float* BX = &Bpts[pp&1][0];
        float tsum = 0.0f, csum = 0.0f;
        for (int p = l; p < 96; p += 64) {
            int pl = (p == 0) ? 0 : p-1;
            int pr = (p == 95) ? 95 : p+1;
            float tax = AX[2*pr]-AX[2*pl], tay = AX[2*pr+1]-AX[2*pl+1];
            float na = fmaxf(sqrtf(tax*tax + tay*tay), 1e-8f);
            float tbx = BX[2*pr]-BX[2*pl], tby = BX[2*pr+1]-BX[2*pl+1];
            float nb = fmaxf(sqrtf(tbx*tbx + tby*tby), 1e-8f);
            tsum += fabsf((tax*tbx + tay*tby) / (na*nb));
            if (p < 94) {
                float psx = AX[2*p+4] - 2.0f*AX[2*p+2] + AX[2*p];
                float psy = AX[2*p+5] - 2.0f*AX[2*p+3] + AX[2*p+1];
                float gsx = BX[2*p+4] - 2.0f*BX[2*p+2] + BX[2*p];
                float gsy = BX[2*p+5] - 2.0f*BX[2*p+3] + BX[2*p+1];
                csum += smooth_l1(psx - gsx) + smooth_l1(psy - gsy);
            }
        }
        #pragma unroll
        for (int off = 32; off > 0; off >>= 1) {
            tsum += __shfl_down(tsum, off);
            csum += __shfl_down(csum, off);
        }
        if (l == 0) { tanLds[pp] = tsum; curvLds[pp] = csum; }
    }

    // ---- mask dot products for the 2x2 tile (batched loads) ----
    const float4* A0 = (const float4*)(ws + PM_OFF + (i0+0) * GRID_N);
    const float4* A1 = (const float4*)(ws + PM_OFF + (i0+1) * GRID_N);
    const float4* B0 = (const float4*)(ws + GM_OFF + (j0+0) * GRID_N);
    const float4* B1 = (const float4*)(ws + GM_OFF + (j0+1) * GRID_N);
    float it00 = 0, it01 = 0, it10 = 0, it11 = 0;
    for (int c0 = 0; c0 < 2304; c0 += 256) {   // 9 batches of 4 chunks
        float4 a0[4], a1[4], b0[4], b1[4];
        #pragma unroll
        for (int u = 0; u < 4; u++) {
            int c = c0 + u*64 + l;
            a0[u] = A0[c]; a1[u] = A1[c]; b0[u] = B0[c]; b1[u] = B1[c];
        }
        #pragma unroll
        for (int u = 0; u < 4; u++) {
            it00 += a0[u].x*b0[u].x + a0[u].y*b0[u].y + a0[u].z*b0[u].z + a0[u].w*b0[u].w;
            it01 += a0[u].x*b1[u].x + a0[u].y*b1[u].y + a0[u].z*b1[u].z + a0[u].w*b1[u].w;
            it10 += a1[u].x*b0[u].x + a1[u].y*b0[u].y + a1[u].z*b0[u].z + a1[u].w*b0[u].w;
            it11 += a1[u].x*b1[u].x + a1[u].y*b1[u].y + a1[u].z*b1[u].z + a1[u].w*b1[u].w;
        }
    }
    #pragma unroll
    for (int off = 32; off > 0; off >>= 1) {
        it00 += __shfl_down(it00, off);
        it01 += __shfl_down(it01, off);
        it10 += __shfl_down(it10, off);
        it11 += __shfl_down(it11, off);
    }
    if (l == 0) { interLds[0]=it00; interLds[1]=it01; interLds[2]=it10; interLds[3]=it11; }
    __syncthreads();

    // ---- finalize 4 outputs ----
    if (l < 4) {
        int r = l >> 1, c = l & 1;
        float sym  = (chamGrp[r][c] + chamGrp[2+c][r]) * (1.0f/192.0f);
        float tanv = 1.0f - tanLds[l] * (1.0f/96.0f);
        float cuv  = curvLds[l] * (1.0f/188.0f);
        float it   = interLds[l];
        const float* pp4 = ws + PMS_OFF + (i0+r)*4;
        const float* gp4 = ws + GMS_OFF + (j0+c)*4;
        float pms = (pp4[0] + pp4[1]) + (pp4[2] + pp4[3]);
        float gms = (gp4[0] + gp4[1]) + (gp4[2] + gp4[3]);
        float uni = pms + gms - it;
        float ovl = 1.0f - it / fmaxf(uni, 1e-8f);
        out[(i0+r) * G_N + (j0+c)] = PTS_W * sym + TAN_W * tanv + CURV_W * cuv + OVL_W * ovl;
    }
}

extern "C" void kernel_launch(void* const* d_in, const int* in_sizes, int n_in,
                              void* d_out, int out_size, void* d_ws, size_t ws_size,
                              hipStream_t stream) {
    (void)in_sizes; (void)n_in; (void)out_size; (void)ws_size;
    const float* pred = (const float*)d_in[0];
    const float* gt   = (const float*)d_in[1];
    const float* vis  = (const float*)d_in[2];
    float* out = (float*)d_out;
    float* ws  = (float*)d_ws;

    prep_kernel<<<Q_N + G_N, 128, 0, stream>>>(pred, gt, vis, ws);
    softmask_kernel<<<(Q_N + G_N) * 9, 256, 0, stream>>>(pred, gt, ws);
    rowsum_kernel<<<(Q_N + G_N) * 4, 256, 0, stream>>>(ws);
    pair_kernel<<<50 * 25, 64, 0, stream>>>(ws, out);
}

// Round 5
// 61.103 us; speedup vs baseline: 3.4725x; 1.3531x over previous
//
#include <hip/hip_runtime.h>
#include <hip/hip_bf16.h>
#include <math.h>

// Problem constants
#define Q_N 100
#define G_N 50
#define P_N 24
#define RS_N 96
#define GRID_N 9216
#define THICK 0.03f
#define SHARP 80.0f
#define PTS_W 5.0f
#define TAN_W 1.0f
#define CURV_W 0.5f
#define OVL_W 2.0f

// Workspace layout (float offsets)
#define PRS_OFF  0                  // pred_rs: 100*192 = 19200
#define GRS_OFF  19200              // gt_rs:   50*192  = 9600  -> 28800
#define PMB_OFF  28800              // PM bf16: 112 x 9216 ushort = 516096 floats -> 544896
#define GMB_OFF  544896             // GM bf16:  64 x 9216 ushort = 294912 floats -> 839808
#define ROWP_OFF 839808             // pred row-sum partials: 100*9 = 900 -> 840708
#define ROWG_OFF 840708             // gt   row-sum partials:  50*9 = 450 -> 841158
#define INTP_OFF 841200             // inter partials: 9 x 112 x 64 = 64512 -> 905712 floats (3.62 MB)

typedef short bf16x8 __attribute__((ext_vector_type(8)));
typedef float f32x4  __attribute__((ext_vector_type(4)));

__device__ __forceinline__ float smooth_l1(float x) {
    float a = fabsf(x);
    return (a < 1.0f) ? 0.5f * a * a : a - 0.5f;
}

__device__ __forceinline__ unsigned short f32_to_bf16(float f) {
    unsigned u = __builtin_bit_cast(unsigned, f);
    unsigned r = u + 0x7FFFu + ((u >> 16) & 1u);   // RNE
    return (unsigned short)(r >> 16);
}
__device__ __forceinline__ float bf16_to_f32(unsigned short s) {
    unsigned u = ((unsigned)s) << 16;
    return __builtin_bit_cast(float, u);
}

// ---------------- Kernel 1: mask + resample (one block per lane) ----------------
__global__ void prep_kernel(const float* __restrict__ pred,
                            const float* __restrict__ gt,
                            const float* __restrict__ vis,
                            float* __restrict__ ws) {
    int lane = blockIdx.x;              // 0..149
    int tid = threadIdx.x;
    bool isPred = lane < Q_N;
    __shared__ float px[P_N], py[P_N], pmask[P_N];
    __shared__ float cum[P_N];
    __shared__ float s_total;

    const float* src = isPred ? pred + lane * (P_N*2) : gt + (lane - Q_N) * (P_N*2);
    if (tid < P_N) {
        float2 p = ((const float2*)src)[tid];
        px[tid] = p.x;
        py[tid] = p.y;
        pmask[tid] = 1.0f;
    }
    __syncthreads();
    if (!isPred && tid == 0) {
        const float* v = vis + (lane - Q_N) * P_N;
        int cnt = 0;
        for (int k = 0; k < P_N; k++) {
            int r = (v[k] > 0.5f) ? 1 : 0;
            cnt += r;
            pmask[k] = (float)r;
        }
        if (cnt < 2) {
            for (int k = 0; k < P_N; k++) pmask[k] = 1.0f;
        }
    }
    __syncthreads();
    if (tid == 0) {
        float c = 0.0f;
        cum[0] = 0.0f;
        for (int k = 0; k < P_N-1; k++) {
            float dx = px[k+1]-px[k], dy = py[k+1]-py[k];
            float dd = dx*dx + dy*dy;
            float len = sqrtf(fmaxf(dd, 1e-12f));        // _safe_norm
            float valid = pmask[k]*pmask[k+1];           // 0 or 1
            c += len * valid;
            cum[k+1] = c;
        }
        s_total = c;
    }
    __syncthreads();
    float total = s_total;
    if (tid < RS_N) {
        float ox, oy;
        if (total < 1e-8f) {
            ox = px[0]; oy = py[0];
        } else {
            float t = ((float)tid / 95.0f) * total;
            // searchsorted(cum, t, side='right') - 1 == count(cum <= t) - 1
            int idx = -1;
            for (int k = 0; k < P_N; k++) idx += (cum[k] <= t) ? 1 : 0;
            idx = min(max(idx, 0), P_N-2);
            float lt = cum[idx], rt = cum[idx+1];
            float alpha = (t - lt) / fmaxf(rt - lt, 1e-8f);
            ox = px[idx] + alpha * (px[idx+1]-px[idx]);
            oy = py[idx] + alpha * (py[idx+1]-py[idx]);
        }
        float* dst = isPred ? ws + PRS_OFF + lane * (RS_N*2)
                            : ws + GRS_OFF + (lane - Q_N) * (RS_N*2);
        dst[2*tid]   = ox;
        dst[2*tid+1] = oy;
    }
}

// ------- Kernel 2: soft masks (bf16) + fused row-sum partials --------
__global__ __launch_bounds__(256)
void softmask_kernel(const float* __restrict__ pred,
                     const float* __restrict__ gt,
                     const float* __restrict__ vis,
                     float* __restrict__ ws) {
    int row   = blockIdx.x / 9;         // 0..149
    int chunk = blockIdx.x % 9;         // 1024 grid pts each
    int tid = threadIdx.x;              // 0..255
    bool isPred = row < Q_N;
    __shared__ float ptx[P_N], pty[P_N], pvv[P_N];
    __shared__ float4 seg[P_N-1];
    __shared__ float  sinv[P_N-1];
    __shared__ int s_noseg;
    __shared__ float wsum[4];

    if (tid < P_N) {
        const float* src = isPred ? pred + row * (P_N*2) : gt + (row - Q_N) * (P_N*2);
        float2 p = ((const float2*)src)[tid];
        ptx[tid] = p.x; pty[tid] = p.y;
    }
    if (tid == 0) {
        s_noseg = 1;
        if (isPred) {
            for (int k = 0; k < P_N; k++) pvv[k] = 1.0f;
        } else {
            const float* v = vis + (row - Q_N) * P_N;
            int cnt = 0;
            for (int k = 0; k < P_N; k++) {
                int r = (v[k] > 0.5f) ? 1 : 0;
                cnt += r;
                pvv[k] = (float)r;
            }
            if (cnt < 2) for (int k = 0; k < P_N; k++) pvv[k] = 1.0f;
        }
    }
    __syncthreads();
    if (tid < P_N-1) {
        bool v = pvv[tid] * pvv[tid+1] > 0.5f;
        if (v) {
            float ax = ptx[tid], ay = pty[tid];
            float abx = ptx[tid+1]-ax, aby = pty[tid+1]-ay;
            seg[tid] = make_float4(ax, ay, abx, aby);
            sinv[tid] = 1.0f / fmaxf(abx*abx + aby*aby, 1e-8f);
            s_noseg = 0;                 // benign race: all writers write 0
        } else {
            seg[tid] = make_float4(1e18f, 1e18f, 0.0f, 0.0f);
            sinv[tid] = 0.0f;
        }
    }
    __syncthreads();

    int g0 = chunk * 1024 + tid * 4;
    float xs[4], ys[4], m2[4];
    #pragma unroll
    for (int u = 0; u < 4; u++) {
        int g = g0 + u;
        xs[u] = (float)(g & 127) * (1.0f/127.0f);
        ys[u] = (float)(g >> 7)  * (1.0f/71.0f);
        m2[u] = 3.0e38f;
    }
    for (int k = 0; k < P_N-1; k++) {
        float4 sg = seg[k];
        float inv = sinv[k];
        #pragma unroll
        for (int u = 0; u < 4; u++) {
            float apx = xs[u] - sg.x, apy = ys[u] - sg.y;
            float t = (apx*sg.z + apy*sg.w) * inv;
            t = fminf(fmaxf(t, 0.0f), 1.0f);
            float dx = apx - t*sg.z, dy = apy - t*sg.w;
            m2[u] = fminf(m2[u], dx*dx + dy*dy);
        }
    }
    if (s_noseg) {
        #pragma unroll
        for (int u = 0; u < 4; u++) m2[u] = 3.0e38f;
        for (int k = 0; k < P_N; k++) {
            if (pvv[k] > 0.5f) {
                #pragma unroll
                for (int u = 0; u < 4; u++) {
                    float dx = xs[u] - ptx[k], dy = ys[u] - pty[k];
                    m2[u] = fminf(m2[u], dx*dx + dy*dy);
                }
            }
        }
    }
    ushort4 o;
    unsigned short* ov = &o.x;
    float lsum = 0.0f;
    #pragma unroll
    for (int u = 0; u < 4; u++) {
        float mind = sqrtf(fmaxf(m2[u], 1e-12f));
        float z = (THICK - mind) * SHARP;
        float s = 1.0f / (1.0f + expf(-z));
        unsigned short h = f32_to_bf16(s);
        ov[u] = h;
        lsum += bf16_to_f32(h);          // row sums consistent with quantized masks
    }
    unsigned short* base = (unsigned short*)(ws + (isPred ? PMB_OFF : GMB_OFF))
                         + (size_t)(isPred ? row : row - Q_N) * GRID_N;
    ((ushort4*)base)[g0 >> 2] = o;

    // deterministic block reduction of lsum
    #pragma unroll
    for (int off = 32; off > 0; off >>= 1) lsum += __shfl_down(lsum, off);
    if ((tid & 63) == 0) wsum[tid >> 6] = lsum;
    __syncthreads();
    if (tid == 0) {
        float s = (wsum[0] + wsum[1]) + (wsum[2] + wsum[3]);
        if (isPred) ws[ROWP_OFF + row*9 + chunk] = s;
        else        ws[ROWG_OFF + (row - Q_N)*9 + chunk] = s;
    }
}

// ------- Kernel 3: inter = PM (bf16) x GM^T (bf16) via MFMA, K-split x9 -------
__global__ __launch_bounds__(64)
void inter_kernel(float* __restrict__ ws) {
    int bid = blockIdx.x;               // 7 x 4 x 9 = 252
    int mt = bid % 7;
    int nt = (bid / 7) & 3;
    int kc = bid / 28;                  // 0..8
    int l = threadIdx.x;
    const unsigned short* PMB = (const unsigned short*)(ws + PMB_OFF);
    const unsigned short* GMB = (const unsigned short*)(ws + GMB_OFF);
    int i0 = mt*16, j0 = nt*16, k0 = kc*1024;
    // A: lane holds PM[i0+(l&15)][k0 + 8*(l>>4) + 32*s .. +7]  (K-contiguous)
    // B: lane holds GM[j0+(l&15)][same k slice]                (B^T layout, K-contiguous)
    const bf16x8* pa = (const bf16x8*)(PMB + (size_t)(i0 + (l & 15)) * GRID_N + k0 + 8*(l >> 4));
    const bf16x8* pb = (const bf16x8*)(GMB + (size_t)(j0 + (l & 15)) * GRID_N + k0 + 8*(l >> 4));
    f32x4 acc = {0.0f, 0.0f, 0.0f, 0.0f};
    #pragma unroll 8
    for (int s = 0; s < 32; s++) {
        acc = __builtin_amdgcn_mfma_f32_16x16x32_bf16(pa[s*4], pb[s*4], acc, 0, 0, 0);
    }
    // D: col = l&15, row = 4*(l>>4) + v
    float* dst = ws + INTP_OFF + kc * 7168;     // 112*64
    int r0 = 4*(l >> 4), c = l & 15;
    #pragma unroll
    for (int v = 0; v < 4; v++) {
        dst[(i0 + r0 + v) * 64 + (j0 + c)] = acc[v];
    }
}

// ------- Kernel 4: one pair per 64-thread block (5000 blocks) -------
__global__ __launch_bounds__(64)
void pair_kernel(const float* __restrict__ ws, float* __restrict__ out) {
    int i = blockIdx.x / G_N;
    int j = blockIdx.x % G_N;
    int l = threadIdx.x;                // 0..63

    // early loads of per-pair precomputed partials (used only at the end)
    float e_ip = 0.0f, e_rp = 0.0f, e_rg = 0.0f;
    if (l < 9) {
        e_ip = ws[INTP_OFF + l*7168 + i*64 + j];
        e_rp = ws[ROWP_OFF + i*9 + l];
        e_rg = ws[ROWG_OFF + j*9 + l];
    }

    __shared__ float Apts[RS_N*2], Bpts[RS_N*2];
    __shared__ float4 Aseg[RS_N-1], Bseg[RS_N-1];
    __shared__ float  AInv[RS_N-1], BInv[RS_N-1];

    const float4* As4 = (const float4*)(ws + PRS_OFF + i * (RS_N*2));
    const float4* Bs4 = (const float4*)(ws + GRS_OFF + j * (RS_N*2));
    {
        int q = l;
        if (q < 48) ((float4*)Apts)[q]    = As4[q];
        else        ((float4*)Bpts)[q-48] = Bs4[q-48];
        int q2 = l + 64;
        if (q2 < 96) ((float4*)Bpts)[q2-48] = Bs4[q2-48];
    }
    __syncthreads();
    for (int q = l; q < 2*(RS_N-1); q += 64) {
        int sideB = (q >= RS_N-1);
        int s = sideB ? q - (RS_N-1) : q;
        const float* P = sideB ? Bpts : Apts;
        float ax = P[2*s], ay = P[2*s+1];
        float abx = P[2*s+2]-ax, aby = P[2*s+3]-ay;
        float inv = 1.0f / fmaxf(abx*abx + aby*aby, 1e-8f);
        if (sideB) { Bseg[s] = make_float4(ax,ay,abx,aby); BInv[s] = inv; }
        else       { Aseg[s] = make_float4(ax,ay,abx,aby); AInv[s] = inv; }
    }
    __syncthreads();

    // chamfer: lanes 0-31 own A pts {3h,3h+1,3h+2} vs B segs; lanes 32-63 own B pts vs A segs
    bool bSide = l >= 32;
    int h = l & 31;
    const float*  myP = bSide ? Bpts : Apts;
    const float4* SG  = bSide ? Aseg : Bseg;
    const float*  SI  = bSide ? AInv : BInv;
    float px0 = myP[6*h+0], py0 = myP[6*h+1];
    float px1 = myP[6*h+2], py1 = myP[6*h+3];
    float px2 = myP[6*h+4], py2 = myP[6*h+5];
    float m20 = 3.0e38f, m21 = 3.0e38f, m22 = 3.0e38f;
    for (int s = 0; s < RS_N-1; s++) {
        float4 sg = SG[s];
        float inv = SI[s];
        {
            float apx = px0-sg.x, apy = py0-sg.y;
            float t = fminf(fmaxf((apx*sg.z + apy*sg.w)*inv, 0.0f), 1.0f);
            float dx = apx - t*sg.z, dy = apy - t*sg.w;
            m20 = fminf(m20, dx*dx + dy*dy);
        }
        {
            float apx = px1-sg.x, apy = py1-sg.y;
            float t = fminf(fmaxf((apx*sg.z + apy*sg.w)*inv, 0.0f), 1.0f);
            float dx = apx - t*sg.z, dy = apy - t*sg.w;
            m21 = fminf(m21, dx*dx + dy*dy);
        }
        {
            float apx = px2-sg.x, apy = py2-sg.y;
            float t = fminf(fmaxf((apx*sg.z + apy*sg.w)*inv, 0.0f), 1.0f);
            float dx = apx - t*sg.z, dy = apy - t*sg.w;
            m22 = fminf(m22, dx*dx + dy*dy);
        }
    }
    float cham = sqrtf(fmaxf(m20, 1e-12f)) + sqrtf(fmaxf(m21, 1e-12f))
               + sqrtf(fmaxf(m22, 1e-12f));

    // tangent + curvature: point-tasks p = l and l+64
    float tsum = 0.0f, csum = 0.0f;
    #pragma unroll
    for (int rep = 0; rep < 2; rep++) {
        int p = l + rep*64;
        if (p < RS_N) {
            int pl = (p == 0) ? 0 : p-1;
            int pr = (p == RS_N-1) ? RS_N-1 : p+1;
            float tax = Apts[2*pr]-Apts[2*pl], tay = Apts[2*pr+1]-Apts[2*pl+1];
            float na = fmaxf(sqrtf(tax*tax + tay*tay), 1e-8f);
            float tbx = Bpts[2*pr]-Bpts[2*pl], tby = Bpts[2*pr+1]-Bpts[2*pl+1];
            float nb = fmaxf(sqrtf(tbx*tbx + tby*tby), 1e-8f);
            tsum += fabsf((tax*tbx + tay*tby) / (na*nb));
            if (p < RS_N-2) {
                float psx = Apts[2*p+4] - 2.0f*Apts[2*p+2] + Apts[2*p];
                float psy = Apts[2*p+5] - 2.0f*Apts[2*p+3] + Apts[2*p+1];
                float gsx = Bpts[2*p+4] - 2.0f*Bpts[2*p+2] + Bpts[2*p];
                float gsy = Bpts[2*p+5] - 2.0f*Bpts[2*p+3] + Bpts[2*p+1];
                csum += smooth_l1(psx - gsx) + smooth_l1(psy - gsy);
            }
        }
    }

    // wave reductions (single wave per block)
    #pragma unroll
    for (int off = 32; off > 0; off >>= 1) {
        cham += __shfl_down(cham, off);
        tsum += __shfl_down(tsum, off);
        csum += __shfl_down(csum, off);
    }
    #pragma unroll
    for (int off = 8; off > 0; off >>= 1) {
        e_ip += __shfl_down(e_ip, off);
        e_rp += __shfl_down(e_rp, off);
        e_rg += __shfl_down(e_rg, off);
    }

    if (l == 0) {
        float sym  = cham * (1.0f/192.0f);
        float tanv = 1.0f - tsum * (1.0f/96.0f);
        float cuv  = csum * (1.0f/188.0f);
        float uni  = e_rp + e_rg - e_ip;
        float ovl  = 1.0f - e_ip / fmaxf(uni, 1e-8f);
        out[i * G_N + j] = PTS_W * sym + TAN_W * tanv + CURV_W * cuv + OVL_W * ovl;
    }
}

extern "C" void kernel_launch(void* const* d_in, const int* in_sizes, int n_in,
                              void* d_out, int out_size, void* d_ws, size_t ws_size,
                              hipStream_t stream) {
    (void)in_sizes; (void)n_in; (void)out_size; (void)ws_size;
    const float* pred = (const float*)d_in[0];
    const float* gt   = (const float*)d_in[1];
    const float* vis  = (const float*)d_in[2];
    float* out = (float*)d_out;
    float* ws  = (float*)d_ws;

    prep_kernel<<<Q_N + G_N, 128, 0, stream>>>(pred, gt, vis, ws);
    softmask_kernel<<<(Q_N + G_N) * 9, 256, 0, stream>>>(pred, gt, vis, ws);
    inter_kernel<<<7 * 4 * 9, 64, 0, stream>>>(ws);
    pair_kernel<<<Q_N * G_N, 64, 0, stream>>>(ws, out);
}

// Round 7
// 58.243 us; speedup vs baseline: 3.6431x; 1.0491x over previous
//
#include <hip/hip_runtime.h>
#include <hip/hip_bf16.h>
#include <math.h>

// Problem constants
#define Q_N 100
#define G_N 50
#define P_N 24
#define RS_N 96
#define GRID_N 9216
#define THICK 0.03f
#define SHARP 80.0f
#define PTS_W 5.0f
#define TAN_W 1.0f
#define CURV_W 0.5f
#define OVL_W 2.0f

// Workspace layout (float offsets) — bf16 regions: nushorts/2 floats!
#define PRS_OFF  0                  // pred_rs: 100*192 = 19200 floats
#define GRS_OFF  19200              // gt_rs:   50*192  = 9600  -> 28800
#define PMB_OFF  28800              // PM bf16: 100*9216 ushort = 460800 floats -> 489600
#define GMB_OFF  489600             // GM bf16:  50*9216 ushort = 230400 floats -> 720000
#define ROWP_OFF 720000             // pred row-sum partials: 100*9 = 900 -> 720900
#define ROWG_OFF 720900             // gt   row-sum partials:  50*9 = 450 -> 721350 (2.89 MB)

__device__ __forceinline__ float smooth_l1(float x) {
    float a = fabsf(x);
    return (a < 1.0f) ? 0.5f * a * a : a - 0.5f;
}

__device__ __forceinline__ unsigned short f32_to_bf16(float f) {
    unsigned u = __builtin_bit_cast(unsigned, f);
    unsigned r = u + 0x7FFFu + ((u >> 16) & 1u);   // RNE
    return (unsigned short)(r >> 16);
}
__device__ __forceinline__ float bf16_to_f32(unsigned short s) {
    unsigned u = ((unsigned)s) << 16;
    return __builtin_bit_cast(float, u);
}
__device__ __forceinline__ float blo(unsigned u) {
    return __builtin_bit_cast(float, u << 16);
}
__device__ __forceinline__ float bhi(unsigned u) {
    return __builtin_bit_cast(float, u & 0xFFFF0000u);
}

// ---- Kernel 1: soft masks (bf16) + row-sum partials + fused resample ----
// grid = 150 rows x 9 chunks; chunk-0 blocks additionally do the arc-length resample.
__global__ __launch_bounds__(256)
void mask_kernel(const float* __restrict__ pred,
                 const float* __restrict__ gt,
                 const float* __restrict__ vis,
                 float* __restrict__ ws) {
    int row   = blockIdx.x / 9;         // 0..149
    int chunk = blockIdx.x % 9;         // 1024 grid pts each
    int tid = threadIdx.x;              // 0..255
    bool isPred = row < Q_N;
    __shared__ float ptx[P_N], pty[P_N], pvv[P_N];
    __shared__ float4 seg[P_N-1];
    __shared__ float  sinv[P_N-1];
    __shared__ int s_noseg;
    __shared__ float wsum[4];
    __shared__ float cum[P_N];
    __shared__ float s_total;

    if (tid < P_N) {
        const float* src = isPred ? pred + row * (P_N*2) : gt + (row - Q_N) * (P_N*2);
        float2 p = ((const float2*)src)[tid];
        ptx[tid] = p.x; pty[tid] = p.y;
    }
    if (tid == 0) {
        s_noseg = 1;
        if (isPred) {
            for (int k = 0; k < P_N; k++) pvv[k] = 1.0f;
        } else {
            const float* v = vis + (row - Q_N) * P_N;
            int cnt = 0;
            for (int k = 0; k < P_N; k++) {
                int r = (v[k] > 0.5f) ? 1 : 0;
                cnt += r;
                pvv[k] = (float)r;
            }
            if (cnt < 2) for (int k = 0; k < P_N; k++) pvv[k] = 1.0f;
        }
    }
    __syncthreads();
    if (tid < P_N-1) {
        bool v = pvv[tid] * pvv[tid+1] > 0.5f;
        if (v) {
            float ax = ptx[tid], ay = pty[tid];
            float abx = ptx[tid+1]-ax, aby = pty[tid+1]-ay;
            seg[tid] = make_float4(ax, ay, abx, aby);
            sinv[tid] = 1.0f / fmaxf(abx*abx + aby*aby, 1e-8f);
            s_noseg = 0;                 // benign race: all writers write 0
        } else {
            seg[tid] = make_float4(1e18f, 1e18f, 0.0f, 0.0f);
            sinv[tid] = 0.0f;
        }
    }
    __syncthreads();

    int g0 = chunk * 1024 + tid * 4;
    float xs[4], ys[4], m2[4];
    #pragma unroll
    for (int u = 0; u < 4; u++) {
        int g = g0 + u;
        xs[u] = (float)(g & 127) * (1.0f/127.0f);
        ys[u] = (float)(g >> 7)  * (1.0f/71.0f);
        m2[u] = 3.0e38f;
    }
    for (int k = 0; k < P_N-1; k++) {
        float4 sg = seg[k];
        float inv = sinv[k];
        #pragma unroll
        for (int u = 0; u < 4; u++) {
            float apx = xs[u] - sg.x, apy = ys[u] - sg.y;
            float t = (apx*sg.z + apy*sg.w) * inv;
            t = fminf(fmaxf(t, 0.0f), 1.0f);
            float dx = apx - t*sg.z, dy = apy - t*sg.w;
            m2[u] = fminf(m2[u], dx*dx + dy*dy);
        }
    }
    if (s_noseg) {
        #pragma unroll
        for (int u = 0; u < 4; u++) m2[u] = 3.0e38f;
        for (int k = 0; k < P_N; k++) {
            if (pvv[k] > 0.5f) {
                #pragma unroll
                for (int u = 0; u < 4; u++) {
                    float dx = xs[u] - ptx[k], dy = ys[u] - pty[k];
                    m2[u] = fminf(m2[u], dx*dx + dy*dy);
                }
            }
        }
    }
    ushort4 o;
    unsigned short* ov = &o.x;
    float lsum = 0.0f;
    #pragma unroll
    for (int u = 0; u < 4; u++) {
        float mind = sqrtf(fmaxf(m2[u], 1e-12f));
        float z = (THICK - mind) * SHARP;
        float s = 1.0f / (1.0f + __expf(-z));
        unsigned short h = f32_to_bf16(s);
        ov[u] = h;
        lsum += bf16_to_f32(h);          // row sums consistent with quantized masks
    }
    unsigned short* base = (unsigned short*)(ws + (isPred ? PMB_OFF : GMB_OFF))
                         + (size_t)(isPred ? row : row - Q_N) * GRID_N;
    ((ushort4*)base)[g0 >> 2] = o;

    // deterministic block reduction of lsum
    #pragma unroll
    for (int off = 32; off > 0; off >>= 1) lsum += __shfl_down(lsum, off);
    if ((tid & 63) == 0) wsum[tid >> 6] = lsum;
    __syncthreads();
    if (tid == 0) {
        float s = (wsum[0] + wsum[1]) + (wsum[2] + wsum[3]);
        if (isPred) ws[ROWP_OFF + row*9 + chunk] = s;
        else        ws[ROWG_OFF + (row - Q_N)*9 + chunk] = s;
    }

    // ---- fused resample: only chunk-0 blocks ----
    if (chunk == 0) {
        if (tid == 0) {
            float c = 0.0f;
            cum[0] = 0.0f;
            for (int k = 0; k < P_N-1; k++) {
                float dx = ptx[k+1]-ptx[k], dy = pty[k+1]-pty[k];
                float len = sqrtf(fmaxf(dx*dx + dy*dy, 1e-12f));  // _safe_norm
                float valid = pvv[k]*pvv[k+1];
                c += len * valid;
                cum[k+1] = c;
            }
            s_total = c;
        }
        __syncthreads();
        float total = s_total;
        if (tid < RS_N) {
            float ox, oy;
            if (total < 1e-8f) {
                ox = ptx[0]; oy = pty[0];
            } else {
                float t = ((float)tid / 95.0f) * total;
                // searchsorted(cum, t, side='right') - 1 == count(cum <= t) - 1
                int idx = -1;
                for (int k = 0; k < P_N; k++) idx += (cum[k] <= t) ? 1 : 0;
                idx = min(max(idx, 0), P_N-2);
                float lt = cum[idx], rt = cum[idx+1];
                float alpha = (t - lt) / fmaxf(rt - lt, 1e-8f);
                ox = ptx[idx] + alpha * (ptx[idx+1]-ptx[idx]);
                oy = pty[idx] + alpha * (pty[idx+1]-pty[idx]);
            }
            float* dst = isPred ? ws + PRS_OFF + row * (RS_N*2)
                                : ws + GRS_OFF + (row - Q_N) * (RS_N*2);
            dst[2*tid]   = ox;
            dst[2*tid+1] = oy;
        }
    }
}

// ---- Kernel 2: one pair per 64-thread block; chamfer + tan + curv + mask dot ----
__global__ __launch_bounds__(64)
void pair_kernel(const float* __restrict__ ws, float* __restrict__ out) {
    int i = blockIdx.x / G_N;
    int j = blockIdx.x % G_N;
    int l = threadIdx.x;                // 0..63

    // early loads of row-sum partials (used only at the end)
    float e_rp = 0.0f, e_rg = 0.0f;
    if (l < 9) {
        e_rp = ws[ROWP_OFF + i*9 + l];
        e_rg = ws[ROWG_OFF + j*9 + l];
    }

    __shared__ float Apts[RS_N*2], Bpts[RS_N*2];
    __shared__ float4 Aseg[RS_N-1], Bseg[RS_N-1];
    __shared__ float  AInv[RS_N-1], BInv[RS_N-1];

    const float4* As4 = (const float4*)(ws + PRS_OFF + i * (RS_N*2));
    const float4* Bs4 = (const float4*)(ws + GRS_OFF + j * (RS_N*2));
    {
        int q = l;
        if (q < 48) ((float4*)Apts)[q]    = As4[q];
        else        ((float4*)Bpts)[q-48] = Bs4[q-48];
        int q2 = l + 64;
        if (q2 < 96) ((float4*)Bpts)[q2-48] = Bs4[q2-48];
    }
    __syncthreads();
    for (int q = l; q < 2*(RS_N-1); q += 64) {
        int sideB = (q >= RS_N-1);
        int s = sideB ? q - (RS_N-1) : q;
        const float* P = sideB ? Bpts : Apts;
        float ax = P[2*s], ay = P[2*s+1];
        float abx = P[2*s+2]-ax, aby = P[2*s+3]-ay;
        float inv = 1.0f / fmaxf(abx*abx + aby*aby, 1e-8f);
        if (sideB) { Bseg[s] = make_float4(ax,ay,abx,aby); BInv[s] = inv; }
        else       { Aseg[s] = make_float4(ax,ay,abx,aby); AInv[s] = inv; }
    }
    __syncthreads();

    // mask intersection dot: bf16 rows from L2 (independent of LDS work)
    const uint4* pa = (const uint4*)((const unsigned short*)(ws + PMB_OFF) + (size_t)i * GRID_N);
    const uint4* pb = (const uint4*)((const unsigned short*)(ws + GMB_OFF) + (size_t)j * GRID_N);
    float dot = 0.0f;
    #pragma unroll 6
    for (int c = 0; c < 18; c++) {      // 18 x 64 lanes x 8 bf16 = 9216
        uint4 a = pa[c*64 + l];
        uint4 b = pb[c*64 + l];
        dot += blo(a.x)*blo(b.x) + bhi(a.x)*bhi(b.x);
        dot += blo(a.y)*blo(b.y) + bhi(a.y)*bhi(b.y);
        dot += blo(a.z)*blo(b.z) + bhi(a.z)*bhi(b.z);
        dot += blo(a.w)*blo(b.w) + bhi(a.w)*bhi(b.w);
    }

    // chamfer: lanes 0-31 own A pts {3h,3h+1,3h+2} vs B segs; lanes 32-63 B pts vs A segs
    bool bSide = l >= 32;
    int h = l & 31;
    const float*  myP = bSide ? Bpts : Apts;
    const float4* SG  = bSide ? Aseg : Bseg;
    const float*  SI  = bSide ? AInv : BInv;
    float px0 = myP[6*h+0], py0 = myP[6*h+1];
    float px1 = myP[6*h+2], py1 = myP[6*h+3];
    float px2 = myP[6*h+4], py2 = myP[6*h+5];
    float m20 = 3.0e38f, m21 = 3.0e38f, m22 = 3.0e38f;
    for (int s = 0; s < RS_N-1; s++) {
        float4 sg = SG[s];
        float inv = SI[s];
        {
            float apx = px0-sg.x, apy = py0-sg.y;
            float t = fminf(fmaxf((apx*sg.z + apy*sg.w)*inv, 0.0f), 1.0f);
            float dx = apx - t*sg.z, dy = apy - t*sg.w;
            m20 = fminf(m20, dx*dx + dy*dy);
        }
        {
            float apx = px1-sg.x, apy = py1-sg.y;
            float t = fminf(fmaxf((apx*sg.z + apy*sg.w)*inv, 0.0f), 1.0f);
            float dx = apx - t*sg.z, dy = apy - t*sg.w;
            m21 = fminf(m21, dx*dx + dy*dy);
        }
        {
            float apx = px2-sg.x, apy = py2-sg.y;
            float t = fminf(fmaxf((apx*sg.z + apy*sg.w)*inv, 0.0f), 1.0f);
            float dx = apx - t*sg.z, dy = apy - t*sg.w;
            m22 = fminf(m22, dx*dx + dy*dy);
        }
    }
    float cham = sqrtf(fmaxf(m20, 1e-12f)) + sqrtf(fmaxf(m21, 1e-12f))
               + sqrtf(fmaxf(m22, 1e-12f));

    // tangent + curvature: point-tasks p = l and l+64
    float tsum = 0.0f, csum = 0.0f;
    #pragma unroll
    for (int rep = 0; rep < 2; rep++) {
        int p = l + rep*64;
        if (p < RS_N) {
            int pl = (p == 0) ? 0 : p-1;
            int pr = (p == RS_N-1) ? RS_N-1 : p+1;
            float tax = Apts[2*pr]-Apts[2*pl], tay = Apts[2*pr+1]-Apts[2*pl+1];
            float na = fmaxf(sqrtf(tax*tax + tay*tay), 1e-8f);
            float tbx = Bpts[2*pr]-Bpts[2*pl], tby = Bpts[2*pr+1]-Bpts[2*pl+1];
            float nb = fmaxf(sqrtf(tbx*tbx + tby*tby), 1e-8f);
            tsum += fabsf((tax*tbx + tay*tby) / (na*nb));
            if (p < RS_N-2) {
                float psx = Apts[2*p+4] - 2.0f*Apts[2*p+2] + Apts[2*p];
                float psy = Apts[2*p+5] - 2.0f*Apts[2*p+3] + Apts[2*p+1];
                float gsx = Bpts[2*p+4] - 2.0f*Bpts[2*p+2] + Bpts[2*p];
                float gsy = Bpts[2*p+5] - 2.0f*Bpts[2*p+3] + Bpts[2*p+1];
                csum += smooth_l1(psx - gsx) + smooth_l1(psy - gsy);
            }
        }
    }

    // wave reductions (single wave per block)
    #pragma unroll
    for (int off = 32; off > 0; off >>= 1) {
        cham += __shfl_down(cham, off);
        tsum += __shfl_down(tsum, off);
        csum += __shfl_down(csum, off);
        dot  += __shfl_down(dot,  off);
    }
    #pragma unroll
    for (int off = 8; off > 0; off >>= 1) {
        e_rp += __shfl_down(e_rp, off);
        e_rg += __shfl_down(e_rg, off);
    }

    if (l == 0) {
        float sym  = cham * (1.0f/192.0f);
        float tanv = 1.0f - tsum * (1.0f/96.0f);
        float cuv  = csum * (1.0f/188.0f);
        float uni  = e_rp + e_rg - dot;
        float ovl  = 1.0f - dot / fmaxf(uni, 1e-8f);
        out[i * G_N + j] = PTS_W * sym + TAN_W * tanv + CURV_W * cuv + OVL_W * ovl;
    }
}

extern "C" void kernel_launch(void* const* d_in, const int* in_sizes, int n_in,
                              void* d_out, int out_size, void* d_ws, size_t ws_size,
                              hipStream_t stream) {
    (void)in_sizes; (void)n_in; (void)out_size; (void)ws_size;
    const float* pred = (const float*)d_in[0];
    const float* gt   = (const float*)d_in[1];
    const float* vis  = (const float*)d_in[2];
    float* out = (float*)d_out;
    float* ws  = (float*)d_ws;

    mask_kernel<<<(Q_N + G_N) * 9, 256, 0, stream>>>(pred, gt, vis, ws);
    pair_kernel<<<Q_N * G_N, 64, 0, stream>>>(ws, out);
}

// Round 8
// 55.577 us; speedup vs baseline: 3.8178x; 1.0480x over previous
//
#include <hip/hip_runtime.h>
#include <hip/hip_bf16.h>
#include <math.h>

// Problem constants
#define Q_N 100
#define G_N 50
#define P_N 24
#define RS_N 96
#define GRID_N 9216
#define THICK 0.03f
#define SHARP 80.0f
#define PTS_W 5.0f
#define TAN_W 1.0f
#define CURV_W 0.5f
#define OVL_W 2.0f

// Workspace layout (float offsets). fp16 mask regions: n_ushorts/2 floats.
#define PRS_OFF  0                  // pred_rs: 100*192 = 19200 floats
#define GRS_OFF  19200              // gt_rs:   50*192  = 9600  -> 28800
#define PMB_OFF  28800              // PM fp16: 100*9216 ushort = 460800 floats -> 489600
#define GMB_OFF  489600             // GM fp16:  50*9216 ushort = 230400 floats -> 720000
#define ROWP_OFF 720000             // pred row-sum partials: 100*9 = 900 -> 720900
#define ROWG_OFF 720900             // gt   row-sum partials:  50*9 = 450 -> 721350 (2.89 MB)

typedef float    f32x2 __attribute__((ext_vector_type(2)));
typedef _Float16 h16x2 __attribute__((ext_vector_type(2)));

__device__ __forceinline__ float smooth_l1(float x) {
    float a = fabsf(x);
    return (a < 1.0f) ? 0.5f * a * a : a - 0.5f;
}

#if __has_builtin(__builtin_amdgcn_fdot2)
__device__ __forceinline__ float fdot2(unsigned a, unsigned b, float c) {
    return __builtin_amdgcn_fdot2(__builtin_bit_cast(h16x2, a),
                                  __builtin_bit_cast(h16x2, b), c, false);
}
#else
__device__ __forceinline__ float fdot2(unsigned a, unsigned b, float c) {
    h16x2 ha = __builtin_bit_cast(h16x2, a);
    h16x2 hb = __builtin_bit_cast(h16x2, b);
    return c + (float)ha.x * (float)hb.x + (float)ha.y * (float)hb.y;
}
#endif

// ---- Kernel 1: soft masks (fp16) + row-sum partials + fused resample ----
// grid = 150 rows x 9 chunks; chunk-0 blocks additionally do the arc-length resample.
__global__ __launch_bounds__(256)
void mask_kernel(const float* __restrict__ pred,
                 const float* __restrict__ gt,
                 const float* __restrict__ vis,
                 float* __restrict__ ws) {
    int row   = blockIdx.x / 9;         // 0..149
    int chunk = blockIdx.x % 9;         // 1024 grid pts each
    int tid = threadIdx.x;              // 0..255
    bool isPred = row < Q_N;
    __shared__ float ptx[P_N], pty[P_N], pvv[P_N];
    __shared__ float4 seg[P_N-1];
    __shared__ float  sinv[P_N-1];
    __shared__ int s_noseg;
    __shared__ float wsum[4];
    __shared__ float cum[P_N];
    __shared__ float s_total;

    if (tid < P_N) {
        const float* src = isPred ? pred + row * (P_N*2) : gt + (row - Q_N) * (P_N*2);
        float2 p = ((const float2*)src)[tid];
        ptx[tid] = p.x; pty[tid] = p.y;
    }
    if (tid == 0) {
        s_noseg = 1;
        if (isPred) {
            for (int k = 0; k < P_N; k++) pvv[k] = 1.0f;
        } else {
            const float* v = vis + (row - Q_N) * P_N;
            int cnt = 0;
            for (int k = 0; k < P_N; k++) {
                int r = (v[k] > 0.5f) ? 1 : 0;
                cnt += r;
                pvv[k] = (float)r;
            }
            if (cnt < 2) for (int k = 0; k < P_N; k++) pvv[k] = 1.0f;
        }
    }
    __syncthreads();
    if (tid < P_N-1) {
        bool v = pvv[tid] * pvv[tid+1] > 0.5f;
        if (v) {
            float ax = ptx[tid], ay = pty[tid];
            float abx = ptx[tid+1]-ax, aby = pty[tid+1]-ay;
            seg[tid] = make_float4(ax, ay, abx, aby);
            sinv[tid] = 1.0f / fmaxf(abx*abx + aby*aby, 1e-8f);
            s_noseg = 0;                 // benign race: all writers write 0
        } else {
            seg[tid] = make_float4(1e18f, 1e18f, 0.0f, 0.0f);
            sinv[tid] = 0.0f;
        }
    }
    __syncthreads();

    int g0 = chunk * 1024 + tid * 4;
    float xs[4], ys[4], m2[4];
    #pragma unroll
    for (int u = 0; u < 4; u++) {
        int g = g0 + u;
        xs[u] = (float)(g & 127) * (1.0f/127.0f);
        ys[u] = (float)(g >> 7)  * (1.0f/71.0f);
        m2[u] = 3.0e38f;
    }
    for (int k = 0; k < P_N-1; k++) {
        float4 sg = seg[k];
        float inv = sinv[k];
        #pragma unroll
        for (int u = 0; u < 4; u++) {
            float apx = xs[u] - sg.x, apy = ys[u] - sg.y;
            float t = (apx*sg.z + apy*sg.w) * inv;
            t = fminf(fmaxf(t, 0.0f), 1.0f);
            float dx = apx - t*sg.z, dy = apy - t*sg.w;
            m2[u] = fminf(m2[u], dx*dx + dy*dy);
        }
    }
    if (s_noseg) {
        #pragma unroll
        for (int u = 0; u < 4; u++) m2[u] = 3.0e38f;
        for (int k = 0; k < P_N; k++) {
            if (pvv[k] > 0.5f) {
                #pragma unroll
                for (int u = 0; u < 4; u++) {
                    float dx = xs[u] - ptx[k], dy = ys[u] - pty[k];
                    m2[u] = fminf(m2[u], dx*dx + dy*dy);
                }
            }
        }
    }
    ushort4 o;
    unsigned short* ov = &o.x;
    float lsum = 0.0f;
    #pragma unroll
    for (int u = 0; u < 4; u++) {
        float mind = sqrtf(fmaxf(m2[u], 1e-12f));
        float z = (THICK - mind) * SHARP;
        float s = 1.0f / (1.0f + __expf(-z));
        _Float16 h = (_Float16)s;                  // RNE f32->f16
        ov[u] = __builtin_bit_cast(unsigned short, h);
        lsum += (float)h;                          // sums consistent with quantized masks
    }
    unsigned short* base = (unsigned short*)(ws + (isPred ? PMB_OFF : GMB_OFF))
                         + (size_t)(isPred ? row : row - Q_N) * GRID_N;
    ((ushort4*)base)[g0 >> 2] = o;

    // deterministic block reduction of lsum
    #pragma unroll
    for (int off = 32; off > 0; off >>= 1) lsum += __shfl_down(lsum, off);
    if ((tid & 63) == 0) wsum[tid >> 6] = lsum;
    __syncthreads();
    if (tid == 0) {
        float s = (wsum[0] + wsum[1]) + (wsum[2] + wsum[3]);
        if (isPred) ws[ROWP_OFF + row*9 + chunk] = s;
        else        ws[ROWG_OFF + (row - Q_N)*9 + chunk] = s;
    }

    // ---- fused resample: only chunk-0 blocks ----
    if (chunk == 0) {
        if (tid == 0) {
            float c = 0.0f;
            cum[0] = 0.0f;
            for (int k = 0; k < P_N-1; k++) {
                float dx = ptx[k+1]-ptx[k], dy = pty[k+1]-pty[k];
                float len = sqrtf(fmaxf(dx*dx + dy*dy, 1e-12f));  // _safe_norm
                float valid = pvv[k]*pvv[k+1];
                c += len * valid;
                cum[k+1] = c;
            }
            s_total = c;
        }
        __syncthreads();
        float total = s_total;
        if (tid < RS_N) {
            float ox, oy;
            if (total < 1e-8f) {
                ox = ptx[0]; oy = pty[0];
            } else {
                float t = ((float)tid / 95.0f) * total;
                // searchsorted(cum, t, side='right') - 1 == count(cum <= t) - 1
                int idx = -1;
                for (int k = 0; k < P_N; k++) idx += (cum[k] <= t) ? 1 : 0;
                idx = min(max(idx, 0), P_N-2);
                float lt = cum[idx], rt = cum[idx+1];
                float alpha = (t - lt) / fmaxf(rt - lt, 1e-8f);
                ox = ptx[idx] + alpha * (ptx[idx+1]-ptx[idx]);
                oy = pty[idx] + alpha * (pty[idx+1]-pty[idx]);
            }
            float* dst = isPred ? ws + PRS_OFF + row * (RS_N*2)
                                : ws + GRS_OFF + (row - Q_N) * (RS_N*2);
            dst[2*tid]   = ox;
            dst[2*tid+1] = oy;
        }
    }
}

// ---- Kernel 2: 2x2 pair tile per 256-thread block (wave w owns one pair) ----
__global__ __launch_bounds__(256)
void pair_kernel(const float* __restrict__ ws, float* __restrict__ out) {
    int bi = blockIdx.x / 25;           // i0 = 2*bi
    int bj = blockIdx.x % 25;           // j0 = 2*bj
    int i0 = bi*2, j0 = bj*2;
    int tid = threadIdx.x;
    int w = tid >> 6;                   // wave 0..3
    int l = tid & 63;
    int wi = w >> 1, wj = w & 1;
    int i = i0 + wi, j = j0 + wj;       // this wave's pair

    __shared__ float Apts[2][RS_N*2], Bpts[2][RS_N*2];
    __shared__ float4 Aseg[2][RS_N-1], Bseg[2][RS_N-1];
    __shared__ float  AInv[2][RS_N-1], BInv[2][RS_N-1];

    // early loads of row-sum partials (used only at the end)
    float e_rp = 0.0f, e_rg = 0.0f;
    if (l < 9) {
        e_rp = ws[ROWP_OFF + i*9 + l];
        e_rg = ws[ROWG_OFF + j*9 + l];
    }

    // stage 4 polylines (192 float4)
    if (tid < 192) {
        int side = tid / 96;            // 0:A 1:B
        int r = (tid / 48) & 1;
        int o = tid % 48;
        const float4* src = (const float4*)(ws + (side ? GRS_OFF + (j0+r)*(RS_N*2)
                                                       : PRS_OFF + (i0+r)*(RS_N*2)));
        ((float4*)(side ? Bpts[r] : Apts[r]))[o] = src[o];
    }
    __syncthreads();
    // build 4 segment tables (380 entries)
    for (int q = tid; q < 4*(RS_N-1); q += 256) {
        int side = q / (2*(RS_N-1));
        int rr = (q / (RS_N-1)) & 1;
        int s = q % (RS_N-1);
        const float* P = side ? Bpts[rr] : Apts[rr];
        float ax = P[2*s], ay = P[2*s+1];
        float abx = P[2*s+2]-ax, aby = P[2*s+3]-ay;
        float inv = 1.0f / fmaxf(abx*abx + aby*aby, 1e-8f);
        if (side) { Bseg[rr][s] = make_float4(ax,ay,abx,aby); BInv[rr][s] = inv; }
        else      { Aseg[rr][s] = make_float4(ax,ay,abx,aby); AInv[rr][s] = inv; }
    }
    __syncthreads();

    // mask intersection dot: fp16 rows via v_dot2_f32_f16
    const uint4* pa = (const uint4*)((const unsigned short*)(ws + PMB_OFF) + (size_t)i * GRID_N);
    const uint4* pb = (const uint4*)((const unsigned short*)(ws + GMB_OFF) + (size_t)j * GRID_N);
    float dot = 0.0f;
    #pragma unroll 6
    for (int c = 0; c < 18; c++) {      // 18 x 64 lanes x 8 fp16 = 9216
        uint4 a = pa[c*64 + l];
        uint4 b = pb[c*64 + l];
        dot = fdot2(a.x, b.x, dot);
        dot = fdot2(a.y, b.y, dot);
        dot = fdot2(a.z, b.z, dot);
        dot = fdot2(a.w, b.w, dot);
    }

    // chamfer: lanes 0-31 A-pts(wi) vs B-segs(wj); lanes 32-63 B-pts(wj) vs A-segs(wi)
    bool bSide = l >= 32;
    int h = l & 31;
    const float*  myP = bSide ? Bpts[wj] : Apts[wi];
    const float4* SG  = bSide ? Aseg[wi] : Bseg[wj];
    const float*  SI  = bSide ? AInv[wi] : BInv[wj];
    // pts 0,1 packed (v_pk_* path), pt 2 scalar
    f32x2 px01 = { myP[6*h+0], myP[6*h+2] };
    f32x2 py01 = { myP[6*h+1], myP[6*h+3] };
    float px2 = myP[6*h+4], py2 = myP[6*h+5];
    float m20 = 3.0e38f, m21 = 3.0e38f, m22 = 3.0e38f;
    for (int s = 0; s < RS_N-1; s++) {
        float4 sg = SG[s];
        float inv = SI[s];
        {
            f32x2 apx = px01 - sg.x;
            f32x2 apy = py01 - sg.y;
            f32x2 dt = apx*sg.z + apy*sg.w;
            f32x2 t = dt * inv;
            t.x = fminf(fmaxf(t.x, 0.0f), 1.0f);
            t.y = fminf(fmaxf(t.y, 0.0f), 1.0f);
            f32x2 dx = apx - t*sg.z;
            f32x2 dy = apy - t*sg.w;
            f32x2 d2 = dx*dx + dy*dy;
            m20 = fminf(m20, d2.x);
            m21 = fminf(m21, d2.y);
        }
        {
            float apx = px2-sg.x, apy = py2-sg.y;
            float t = fminf(fmaxf((apx*sg.z + apy*sg.w)*inv, 0.0f), 1.0f);
            float dx = apx - t*sg.z, dy = apy - t*sg.w;
            m22 = fminf(m22, dx*dx + dy*dy);
        }
    }
    float cham = sqrtf(fmaxf(m20, 1e-12f)) + sqrtf(fmaxf(m21, 1e-12f))
               + sqrtf(fmaxf(m22, 1e-12f));

    // tangent + curvature: point-tasks p = l and l+64 (within this wave's pair)
    const float* AX = Apts[wi];
    const float* BX = Bpts[wj];
    float tsum = 0.0f, csum = 0.0f;
    #pragma unroll
    for (int rep = 0; rep < 2; rep++) {
        int p = l + rep*64;
        if (p < RS_N) {
            int pl = (p == 0) ? 0 : p-1;
            int pr = (p == RS_N-1) ? RS_N-1 : p+1;
            float tax = AX[2*pr]-AX[2*pl], tay = AX[2*pr+1]-AX[2*pl+1];
            float na = fmaxf(sqrtf(tax*tax + tay*tay), 1e-8f);
            float tbx = BX[2*pr]-BX[2*pl], tby = BX[2*pr+1]-BX[2*pl+1];
            float nb = fmaxf(sqrtf(tbx*tbx + tby*tby), 1e-8f);
            tsum += fabsf((tax*tbx + tay*tby) / (na*nb));
            if (p < RS_N-2) {
                float psx = AX[2*p+4] - 2.0f*AX[2*p+2] + AX[2*p];
                float psy = AX[2*p+5] - 2.0f*AX[2*p+3] + AX[2*p+1];
                float gsx = BX[2*p+4] - 2.0f*BX[2*p+2] + BX[2*p];
                float gsy = BX[2*p+5] - 2.0f*BX[2*p+3] + BX[2*p+1];
                csum += smooth_l1(psx - gsx) + smooth_l1(psy - gsy);
            }
        }
    }

    // per-wave reductions
    #pragma unroll
    for (int off = 32; off > 0; off >>= 1) {
        cham += __shfl_down(cham, off);
        tsum += __shfl_down(tsum, off);
        csum += __shfl_down(csum, off);
        dot  += __shfl_down(dot,  off);
    }
    #pragma unroll
    for (int off = 8; off > 0; off >>= 1) {
        e_rp += __shfl_down(e_rp, off);
        e_rg += __shfl_down(e_rg, off);
    }

    if (l == 0) {
        float sym  = cham * (1.0f/192.0f);
        float tanv = 1.0f - tsum * (1.0f/96.0f);
        float cuv  = csum * (1.0f/188.0f);
        float uni  = e_rp + e_rg - dot;
        float ovl  = 1.0f - dot / fmaxf(uni, 1e-8f);
        out[i * G_N + j] = PTS_W * sym + TAN_W * tanv + CURV_W * cuv + OVL_W * ovl;
    }
}

extern "C" void kernel_launch(void* const* d_in, const int* in_sizes, int n_in,
                              void* d_out, int out_size, void* d_ws, size_t ws_size,
                              hipStream_t stream) {
    (void)in_sizes; (void)n_in; (void)out_size; (void)ws_size;
    const float* pred = (const float*)d_in[0];
    const float* gt   = (const float*)d_in[1];
    const float* vis  = (const float*)d_in[2];
    float* out = (float*)d_out;
    float* ws  = (float*)d_ws;

    mask_kernel<<<(Q_N + G_N) * 9, 256, 0, stream>>>(pred, gt, vis, ws);
    pair_kernel<<<50 * 25, 256, 0, stream>>>(ws, out);
}

// Round 9
// 46.530 us; speedup vs baseline: 4.5602x; 1.1944x over previous
//
#include <hip/hip_runtime.h>
#include <hip/hip_bf16.h>
#include <math.h>

// Problem constants
#define Q_N 100
#define G_N 50
#define P_N 24
#define RS_N 96
#define GRID_N 9216
#define THICK 0.03f
#define SHARP 80.0f
#define PTS_W 5.0f
#define TAN_W 1.0f
#define CURV_W 0.5f
#define OVL_W 2.0f

// Workspace layout (float offsets). fp16 regions: n_ushorts/2 floats.
// PM padded to 112 rows, GM to 64 rows for 16x16 MFMA tiles (pad reads garbage,
// never flows into valid (i<100,j<50) outputs).
#define PRS_OFF  0                  // pred_rs: 100*192 = 19200 floats
#define GRS_OFF  19200              // gt_rs:   50*192  = 9600  -> 28800
#define PMB_OFF  28800              // PM fp16: 112*9216 ushort = 516096 f -> 544896
#define GMB_OFF  544896             // GM fp16:  64*9216 ushort = 294912 f -> 839808
#define ROWP_OFF 839808             // pred row-sum partials: 100*9 -> 840708
#define ROWG_OFF 840708             // gt   row-sum partials:  50*9 -> 841158
#define INTP_OFF 841216             // inter partials: 9 x 112 x 64 = 64512 -> 905728 (3.62 MB)

typedef float    f32x2 __attribute__((ext_vector_type(2)));
typedef float    f32x4 __attribute__((ext_vector_type(4)));
typedef _Float16 f16x8 __attribute__((ext_vector_type(8)));

__device__ __forceinline__ float smooth_l1(float x) {
    float a = fabsf(x);
    return (a < 1.0f) ? 0.5f * a * a : a - 0.5f;
}
__device__ __forceinline__ float fast_rcp(float x) {
#if __has_builtin(__builtin_amdgcn_rcpf)
    return __builtin_amdgcn_rcpf(x);
#else
    return 1.0f / x;
#endif
}
__device__ __forceinline__ float fast_sqrt(float x) {
#if __has_builtin(__builtin_amdgcn_sqrtf)
    return __builtin_amdgcn_sqrtf(x);
#else
    return sqrtf(x);
#endif
}

// ---- Kernel 1: soft masks (fp16) + row-sum partials + fused resample ----
__global__ __launch_bounds__(256)
void mask_kernel(const float* __restrict__ pred,
                 const float* __restrict__ gt,
                 const float* __restrict__ vis,
                 float* __restrict__ ws) {
    int row   = blockIdx.x / 9;         // 0..149
    int chunk = blockIdx.x % 9;         // 1024 grid pts each
    int tid = threadIdx.x;              // 0..255
    bool isPred = row < Q_N;
    __shared__ float ptx[P_N], pty[P_N], pvv[P_N];
    __shared__ float4 seg[P_N-1];
    __shared__ float  sinv[P_N-1];
    __shared__ int s_noseg;
    __shared__ float wsum[4];
    __shared__ float cum[P_N];
    __shared__ float s_total;

    if (tid < P_N) {
        const float* src = isPred ? pred + row * (P_N*2) : gt + (row - Q_N) * (P_N*2);
        float2 p = ((const float2*)src)[tid];
        ptx[tid] = p.x; pty[tid] = p.y;
    }
    if (tid == 0) {
        s_noseg = 1;
        if (isPred) {
            for (int k = 0; k < P_N; k++) pvv[k] = 1.0f;
        } else {
            const float* v = vis + (row - Q_N) * P_N;
            int cnt = 0;
            for (int k = 0; k < P_N; k++) {
                int r = (v[k] > 0.5f) ? 1 : 0;
                cnt += r;
                pvv[k] = (float)r;
            }
            if (cnt < 2) for (int k = 0; k < P_N; k++) pvv[k] = 1.0f;
        }
    }
    __syncthreads();
    if (tid < P_N-1) {
        bool v = pvv[tid] * pvv[tid+1] > 0.5f;
        if (v) {
            float ax = ptx[tid], ay = pty[tid];
            float abx = ptx[tid+1]-ax, aby = pty[tid+1]-ay;
            seg[tid] = make_float4(ax, ay, abx, aby);
            sinv[tid] = fast_rcp(fmaxf(abx*abx + aby*aby, 1e-8f));
            s_noseg = 0;                 // benign race: all writers write 0
        } else {
            seg[tid] = make_float4(1e18f, 1e18f, 0.0f, 0.0f);
            sinv[tid] = 0.0f;
        }
    }
    __syncthreads();

    int g0 = chunk * 1024 + tid * 4;    // 4 consecutive grid pts, same grid row
    float y  = (float)(g0 >> 7) * (1.0f/71.0f);
    float x0 = (float)(g0 & 127) * (1.0f/127.0f);
    f32x2 xs01 = { x0,                  x0 + 1.0f/127.0f };
    f32x2 xs23 = { x0 + 2.0f/127.0f,    x0 + 3.0f/127.0f };
    f32x2 m01 = {3.0e38f, 3.0e38f}, m23 = {3.0e38f, 3.0e38f};
    #pragma unroll
    for (int k = 0; k < P_N-1; k++) {
        float4 sg = seg[k];
        float inv = sinv[k];
        float apy = y - sg.y;
        float dwy = apy * sg.w;
        f32x2 apx01 = xs01 - sg.x;
        f32x2 apx23 = xs23 - sg.x;
        f32x2 t01 = (apx01*sg.z + dwy) * inv;
        f32x2 t23 = (apx23*sg.z + dwy) * inv;
        t01.x = fminf(fmaxf(t01.x, 0.0f), 1.0f);
        t01.y = fminf(fmaxf(t01.y, 0.0f), 1.0f);
        t23.x = fminf(fmaxf(t23.x, 0.0f), 1.0f);
        t23.y = fminf(fmaxf(t23.y, 0.0f), 1.0f);
        f32x2 dx01 = apx01 - t01*sg.z;
        f32x2 dy01 = apy   - t01*sg.w;
        f32x2 dx23 = apx23 - t23*sg.z;
        f32x2 dy23 = apy   - t23*sg.w;
        f32x2 d01 = dx01*dx01 + dy01*dy01;
        f32x2 d23 = dx23*dx23 + dy23*dy23;
        m01.x = fminf(m01.x, d01.x); m01.y = fminf(m01.y, d01.y);
        m23.x = fminf(m23.x, d23.x); m23.y = fminf(m23.y, d23.y);
    }
    float m2[4] = { m01.x, m01.y, m23.x, m23.y };
    if (s_noseg) {
        float xs[4] = { xs01.x, xs01.y, xs23.x, xs23.y };
        #pragma unroll
        for (int u = 0; u < 4; u++) m2[u] = 3.0e38f;
        for (int k = 0; k < P_N; k++) {
            if (pvv[k] > 0.5f) {
                #pragma unroll
                for (int u = 0; u < 4; u++) {
                    float dx = xs[u] - ptx[k], dy = y - pty[k];
                    m2[u] = fminf(m2[u], dx*dx + dy*dy);
                }
            }
        }
    }
    ushort4 o;
    unsigned short* ov = &o.x;
    float lsum = 0.0f;
    #pragma unroll
    for (int u = 0; u < 4; u++) {
        float mind = fast_sqrt(fmaxf(m2[u], 1e-12f));
        float z = (THICK - mind) * SHARP;
        float s = fast_rcp(1.0f + __expf(-z));
        _Float16 h = (_Float16)s;                  // RNE f32->f16
        ov[u] = __builtin_bit_cast(unsigned short, h);
        lsum += (float)h;                          // sums consistent with quantized masks
    }
    unsigned short* base = (unsigned short*)(ws + (isPred ? PMB_OFF : GMB_OFF))
                         + (size_t)(isPred ? row : row - Q_N) * GRID_N;
    ((ushort4*)base)[g0 >> 2] = o;

    // deterministic block reduction of lsum
    #pragma unroll
    for (int off = 32; off > 0; off >>= 1) lsum += __shfl_down(lsum, off);
    if ((tid & 63) == 0) wsum[tid >> 6] = lsum;
    __syncthreads();
    if (tid == 0) {
        float s = (wsum[0] + wsum[1]) + (wsum[2] + wsum[3]);
        if (isPred) ws[ROWP_OFF + row*9 + chunk] = s;
        else        ws[ROWG_OFF + (row - Q_N)*9 + chunk] = s;
    }

    // ---- fused resample: only chunk-0 blocks ----
    if (chunk == 0) {
        if (tid == 0) {
            float c = 0.0f;
            cum[0] = 0.0f;
            for (int k = 0; k < P_N-1; k++) {
                float dx = ptx[k+1]-ptx[k], dy = pty[k+1]-pty[k];
                float len = sqrtf(fmaxf(dx*dx + dy*dy, 1e-12f));  // _safe_norm (keep IEEE)
                float valid = pvv[k]*pvv[k+1];
                c += len * valid;
                cum[k+1] = c;
            }
            s_total = c;
        }
        __syncthreads();
        float total = s_total;
        if (tid < RS_N) {
            float ox, oy;
            if (total < 1e-8f) {
                ox = ptx[0]; oy = pty[0];
            } else {
                float t = ((float)tid / 95.0f) * total;
                // searchsorted(cum, t, side='right') - 1 == count(cum <= t) - 1
                int idx = -1;
                for (int k = 0; k < P_N; k++) idx += (cum[k] <= t) ? 1 : 0;
                idx = min(max(idx, 0), P_N-2);
                float lt = cum[idx], rt = cum[idx+1];
                float alpha = (t - lt) / fmaxf(rt - lt, 1e-8f);
                ox = ptx[idx] + alpha * (ptx[idx+1]-ptx[idx]);
                oy = pty[idx] + alpha * (pty[idx+1]-pty[idx]);
            }
            float* dst = isPred ? ws + PRS_OFF + row * (RS_N*2)
                                : ws + GRS_OFF + (row - Q_N) * (RS_N*2);
            dst[2*tid]   = ox;
            dst[2*tid+1] = oy;
        }
    }
}

// ---- Kernel 2: inter = PM (fp16) x GM^T (fp16) via MFMA, K-split x9 ----
__global__ __launch_bounds__(64)
void inter_kernel(float* __restrict__ ws) {
    int bid = blockIdx.x;               // 7 x 4 x 9 = 252
    int mt = bid % 7;
    int nt = (bid / 7) & 3;
    int kc = bid / 28;                  // 0..8
    int l = threadIdx.x;
    const unsigned short* PMB = (const unsigned short*)(ws + PMB_OFF);
    const unsigned short* GMB = (const unsigned short*)(ws + GMB_OFF);
    int i0 = mt*16, j0 = nt*16, k0 = kc*1024;
    const f16x8* pa = (const f16x8*)(PMB + (size_t)(i0 + (l & 15)) * GRID_N + k0 + 8*(l >> 4));
    const f16x8* pb = (const f16x8*)(GMB + (size_t)(j0 + (l & 15)) * GRID_N + k0 + 8*(l >> 4));
    f32x4 acc = {0.0f, 0.0f, 0.0f, 0.0f};
    #pragma unroll 8
    for (int s = 0; s < 32; s++) {
        acc = __builtin_amdgcn_mfma_f32_16x16x32_f16(pa[s*4], pb[s*4], acc, 0, 0, 0);
    }
    // D: col = l&15, row = 4*(l>>4) + v
    float* dst = ws + INTP_OFF + kc * 7168;     // 112*64
    int r0 = 4*(l >> 4), c = l & 15;
    #pragma unroll
    for (int v = 0; v < 4; v++) {
        dst[(i0 + r0 + v) * 64 + (j0 + c)] = acc[v];
    }
}

// ---- Kernel 3: 2x2 pair tile per 256-thread block (wave w owns one pair) ----
__global__ __launch_bounds__(256)
void pair_kernel(const float* __restrict__ ws, float* __restrict__ out) {
    int bi = blockIdx.x / 25;           // i0 = 2*bi
    int bj = blockIdx.x % 25;           // j0 = 2*bj
    int i0 = bi*2, j0 = bj*2;
    int tid = threadIdx.x;
    int w = tid >> 6;                   // wave 0..3
    int l = tid & 63;
    int wi = w >> 1, wj = w & 1;
    int i = i0 + wi, j = j0 + wj;       // this wave's pair

    __shared__ float Apts[2][RS_N*2], Bpts[2][RS_N*2];
    __shared__ float4 Aseg[2][RS_N-1], Bseg[2][RS_N-1];
    __shared__ float  AInv[2][RS_N-1], BInv[2][RS_N-1];

    // early loads of precomputed partials (latency hidden under staging)
    float e_ip = 0.0f, e_rp = 0.0f, e_rg = 0.0f;
    if (l < 9) {
        e_ip = ws[INTP_OFF + l*7168 + i*64 + j];
        e_rp = ws[ROWP_OFF + i*9 + l];
        e_rg = ws[ROWG_OFF + j*9 + l];
    }

    // stage 4 polylines (192 float4)
    if (tid < 192) {
        int side = tid / 96;            // 0:A 1:B
        int r = (tid / 48) & 1;
        int o = tid % 48;
        const float4* src = (const float4*)(ws + (side ? GRS_OFF + (j0+r)*(RS_N*2)
                                                       : PRS_OFF + (i0+r)*(RS_N*2)));
        ((float4*)(side ? Bpts[r] : Apts[r]))[o] = src[o];
    }
    __syncthreads();
    // build 4 segment tables (380 entries)
    for (int q = tid; q < 4*(RS_N-1); q += 256) {
        int side = q / (2*(RS_N-1));
        int rr = (q / (RS_N-1)) & 1;
        int s = q % (RS_N-1);
        const float* P = side ? Bpts[rr] : Apts[rr];
        float ax = P[2*s], ay = P[2*s+1];
        float abx = P[2*s+2]-ax, aby = P[2*s+3]-ay;
        float inv = fast_rcp(fmaxf(abx*abx + aby*aby, 1e-8f));
        if (side) { Bseg[rr][s] = make_float4(ax,ay,abx,aby); BInv[rr][s] = inv; }
        else      { Aseg[rr][s] = make_float4(ax,ay,abx,aby); AInv[rr][s] = inv; }
    }
    __syncthreads();

    // chamfer: lanes 0-31 A-pts(wi) vs B-segs(wj); lanes 32-63 B-pts(wj) vs A-segs(wi)
    bool bSide = l >= 32;
    int h = l & 31;
    const float*  myP = bSide ? Bpts[wj] : Apts[wi];
    const float4* SG  = bSide ? Aseg[wi] : Bseg[wj];
    const float*  SI  = bSide ? AInv[wi] : BInv[wj];
    f32x2 px01 = { myP[6*h+0], myP[6*h+2] };
    f32x2 py01 = { myP[6*h+1], myP[6*h+3] };
    float px2 = myP[6*h+4], py2 = myP[6*h+5];
    f32x2 m01 = {3.0e38f, 3.0e38f};
    float m22 = 3.0e38f;
    #pragma unroll 5
    for (int s = 0; s < RS_N-1; s++) {
        float4 sg = SG[s];
        float inv = SI[s];
        {
            f32x2 apx = px01 - sg.x;
            f32x2 apy = py01 - sg.y;
            f32x2 t = (apx*sg.z + apy*sg.w) * inv;
            t.x = fminf(fmaxf(t.x, 0.0f), 1.0f);
            t.y = fminf(fmaxf(t.y, 0.0f), 1.0f);
            f32x2 dx = apx - t*sg.z;
            f32x2 dy = apy - t*sg.w;
            f32x2 d2 = dx*dx + dy*dy;
            m01.x = fminf(m01.x, d2.x);
            m01.y = fminf(m01.y, d2.y);
        }
        {
            float apx = px2-sg.x, apy = py2-sg.y;
            float t = fminf(fmaxf((apx*sg.z + apy*sg.w)*inv, 0.0f), 1.0f);
            float dx = apx - t*sg.z, dy = apy - t*sg.w;
            m22 = fminf(m22, dx*dx + dy*dy);
        }
    }
    float cham = fast_sqrt(fmaxf(m01.x, 1e-12f)) + fast_sqrt(fmaxf(m01.y, 1e-12f))
               + fast_sqrt(fmaxf(m22, 1e-12f));

    // tangent + curvature: point-tasks p = l and l+64 (within this wave's pair)
    const float* AX = Apts[wi];
    const float* BX = Bpts[wj];
    float tsum = 0.0f, csum = 0.0f;
    #pragma unroll
    for (int rep = 0; rep < 2; rep++) {
        int p = l + rep*64;
        if (p < RS_N) {
            int pl = (p == 0) ? 0 : p-1;
            int pr = (p == RS_N-1) ? RS_N-1 : p+1;
            float tax = AX[2*pr]-AX[2*pl], tay = AX[2*pr+1]-AX[2*pl+1];
            float na = fmaxf(fast_sqrt(tax*tax + tay*tay), 1e-8f);
            float tbx = BX[2*pr]-BX[2*pl], tby = BX[2*pr+1]-BX[2*pl+1];
            float nb = fmaxf(fast_sqrt(tbx*tbx + tby*tby), 1e-8f);
            tsum += fabsf((tax*tbx + tay*tby) * fast_rcp(na*nb));
            if (p < RS_N-2) {
                float psx = AX[2*p+4] - 2.0f*AX[2*p+2] + AX[2*p];
                float psy = AX[2*p+5] - 2.0f*AX[2*p+3] + AX[2*p+1];
                float gsx = BX[2*p+4] - 2.0f*BX[2*p+2] + BX[2*p];
                float gsy = BX[2*p+5] - 2.0f*BX[2*p+3] + BX[2*p+1];
                csum += smooth_l1(psx - gsx) + smooth_l1(psy - gsy);
            }
        }
    }

    // per-wave reductions
    #pragma unroll
    for (int off = 32; off > 0; off >>= 1) {
        cham += __shfl_down(cham, off);
        tsum += __shfl_down(tsum, off);
        csum += __shfl_down(csum, off);
    }
    #pragma unroll
    for (int off = 8; off > 0; off >>= 1) {
        e_ip += __shfl_down(e_ip, off);
        e_rp += __shfl_down(e_rp, off);
        e_rg += __shfl_down(e_rg, off);
    }

    if (l == 0) {
        float sym  = cham * (1.0f/192.0f);
        float tanv = 1.0f - tsum * (1.0f/96.0f);
        float cuv  = csum * (1.0f/188.0f);
        float uni  = e_rp + e_rg - e_ip;
        float ovl  = 1.0f - e_ip / fmaxf(uni, 1e-8f);
        out[i * G_N + j] = PTS_W * sym + TAN_W * tanv + CURV_W * cuv + OVL_W * ovl;
    }
}

extern "C" void kernel_launch(void* const* d_in, const int* in_sizes, int n_in,
                              void* d_out, int out_size, void* d_ws, size_t ws_size,
                              hipStream_t stream) {
    (void)in_sizes; (void)n_in; (void)out_size; (void)ws_size;
    const float* pred = (const float*)d_in[0];
    const float* gt   = (const float*)d_in[1];
    const float* vis  = (const float*)d_in[2];
    float* out = (float*)d_out;
    float* ws  = (float*)d_ws;

    mask_kernel<<<(Q_N + G_N) * 9, 256, 0, stream>>>(pred, gt, vis, ws);
    inter_kernel<<<7 * 4 * 9, 64, 0, stream>>>(ws);
    pair_kernel<<<50 * 25, 256, 0, stream>>>(ws, out);
}